// Round 15
// baseline (257.219 us; speedup 1.0000x reference)
//
#include <hip/hip_runtime.h>
#include <hip/hip_bf16.h>
#include <math.h>

// Problem constants (N_WAY=64, K_SHOT=5, Q_QUERY=128, D_FEAT=128)
#define M     8192      // n*q query rows
#define D     128       // feature dim
#define NCLS  64        // n classes
#define KSHOT 5
#define XROW  133       // (k+q) rows per class in x
#define KTOP  9
#define EPSV  1e-8f

// Threshold filter + exact certificate (R13, proven):
//   k2f appends j with bf16-approx sim >= TAU_LO. k_rerank computes EXACT fp32
//   dots of all candidates, certifies iff exact-9th-among-candidates >
//   TAU_LO+EPS_DOT (=> true top-9 provably subset). Cert-fail P ~ 1e-13/row;
//   k_fb exact full-row backstop.
#define TAU_LO  0.21f
#define EPS_DOT 0.005f
#define CAP     160     // candidate capacity (mean ~72, overflow P~1e-20)

// k2f: MFMA filter pass. Block = 64 i (4 waves x 16-i subs) x 512 j (SJ=16).
// Barrier-free; A-frags from global (L2-resident qh) with a 2-deep register
// pipeline (R13 lesson: no prefetch -> full L2 latency per tile -> 141us at
// 8% VALUBusy; R12's prefetched version was ~3x faster).
#define SJ    16
#define JPB   (M / SJ)      // 512 j per block
#define NTIL  (JPB / 16)    // 32 j-tiles of 16

typedef __attribute__((__ext_vector_type__(8))) short bf16v8;  // 8 bf16 = 4 VGPR
typedef __attribute__((__ext_vector_type__(4))) float f32v4;

// ---------------------------------------------------------------------------
// register-resident top-K with (value desc, index asc) tie-break, matching
// jax.lax.top_k set semantics; arrival-order independent for distinct indices.
template <int KN>
__device__ __forceinline__ void topk_insert(float (&kv)[KN], int (&ki)[KN],
                                            float v, int j) {
  if (v > kv[KN - 1] || (v == kv[KN - 1] && j < ki[KN - 1])) {
    float cv = v; int cj = j;
#pragma unroll
    for (int t = 0; t < KN; ++t) {
      bool b = (cv > kv[t]) || (cv == kv[t] && cj < ki[t]);
      float tv = kv[t]; int ti_ = ki[t];
      kv[t] = b ? cv : tv;  ki[t] = b ? cj : ti_;
      cv   = b ? tv : cv;   cj   = b ? ti_ : cj;
    }
  }
}

// ---------------------------------------------------------------------------
__global__ void k0_proto(const float* __restrict__ x, float* __restrict__ protnT) {
  int c = blockIdx.x;
  int lane = threadIdx.x;
  const float* base = x + (size_t)(c * XROW) * D;
  float a0 = 0.f, a1 = 0.f;
#pragma unroll
  for (int s = 0; s < KSHOT; ++s) {
    a0 += base[s * D + lane];
    a1 += base[s * D + 64 + lane];
  }
  a0 *= 0.2f; a1 *= 0.2f;
  float ss = a0 * a0 + a1 * a1;
#pragma unroll
  for (int off = 1; off < 64; off <<= 1) ss += __shfl_xor(ss, off);
  float rn = 1.0f / fmaxf(sqrtf(ss), EPSV);
  protnT[lane * NCLS + c]        = a0 * rn;
  protnT[(lane + 64) * NCLS + c] = a1 * rn;
}

// ---------------------------------------------------------------------------
// k1: L2-normalize query rows -> qn (f32) and qh (bf16).
__global__ void k1_qnorm(const float* __restrict__ x, float* __restrict__ qn,
                         short* __restrict__ qh) {
  int lane = threadIdx.x & 63;
  int wv = threadIdx.x >> 6;
  int r = blockIdx.x * 4 + wv;
  int xr = (r >> 7) * XROW + KSHOT + (r & 127);
  const float* src = x + (size_t)xr * D;
  float v0 = src[lane], v1 = src[64 + lane];
  float ss = v0 * v0 + v1 * v1;
#pragma unroll
  for (int off = 1; off < 64; off <<= 1) ss += __shfl_xor(ss, off);
  float rn = 1.0f / fmaxf(sqrtf(ss), EPSV);
  float q0 = v0 * rn, q1 = v1 * rn;
  qn[(size_t)r * D + lane]      = q0;
  qn[(size_t)r * D + 64 + lane] = q1;
  __hip_bfloat16 h0 = __float2bfloat16(q0);
  __hip_bfloat16 h1 = __float2bfloat16(q1);
  qh[(size_t)r * D + lane]      = *(short*)&h0;
  qh[(size_t)r * D + 64 + lane] = *(short*)&h1;
}

// ---------------------------------------------------------------------------
// k2f: bf16 MFMA + threshold filter, barrier-free, 2-deep reg pipeline.
// D layout (m89-verified): i-col = lane&15, j-row = (lane>>4)*4 + reg.
__global__ __launch_bounds__(256) void
k2f(const short* __restrict__ qh, int* __restrict__ cnt, int* __restrict__ cand) {
  const int tid  = threadIdx.x;
  const int l    = tid & 63;
  const int w    = tid >> 6;
  const int ib   = blockIdx.x >> 4;        // 128 i-strips of 64
  const int js   = blockIdx.x & (SJ - 1);  // 16 j-splits
  const int i0   = ib * 64;
  const int j0s  = js * JPB;

  const bf16v8* qh8 = (const bf16v8*)qh;
  const int lg   = l >> 4;                 // k-group 0..3
  const int arow = l & 15;
  const int myi  = i0 + w * 16 + arow;     // this lane's i-row

  // persistent i-side B fragments: lane's i-row, 4 k-windows
  bf16v8 bh[4];
#pragma unroll
  for (int kk = 0; kk < 4; ++kk)
    bh[kk] = qh8[(size_t)myi * 16 + kk * 4 + lg];

#define LOADT(dst0, dst1, dst2, dst3, tt)                                   \
  {                                                                         \
    const size_t jr16_ = (size_t)(j0s + (tt) * 16 + arow) * 16;             \
    dst0 = qh8[jr16_ + 0 + lg];                                             \
    dst1 = qh8[jr16_ + 4 + lg];                                             \
    dst2 = qh8[jr16_ + 8 + lg];                                             \
    dst3 = qh8[jr16_ + 12 + lg];                                            \
  }

#define BODY(c0, c1, c2, c3, tt)                                            \
  {                                                                         \
    f32v4 a0_ = {0.f, 0.f, 0.f, 0.f};                                       \
    f32v4 a1_ = {0.f, 0.f, 0.f, 0.f};                                       \
    a0_ = __builtin_amdgcn_mfma_f32_16x16x32_bf16(c0, bh[0], a0_, 0, 0, 0); \
    a1_ = __builtin_amdgcn_mfma_f32_16x16x32_bf16(c1, bh[1], a1_, 0, 0, 0); \
    a0_ = __builtin_amdgcn_mfma_f32_16x16x32_bf16(c2, bh[2], a0_, 0, 0, 0); \
    a1_ = __builtin_amdgcn_mfma_f32_16x16x32_bf16(c3, bh[3], a1_, 0, 0, 0); \
    f32v4 s_ = a0_ + a1_;                                                   \
    const int jb_ = j0s + (tt) * 16 + lg * 4;                               \
    _Pragma("unroll")                                                       \
    for (int u = 0; u < 4; ++u) {                                           \
      if (s_[u] >= TAU_LO) {                                                \
        int slot_ = atomicAdd(&cnt[myi], 1);                                \
        if (slot_ < CAP) cand[(size_t)myi * CAP + slot_] = jb_ + u;         \
      }                                                                     \
    }                                                                       \
  }

  // 2-deep pipeline: tiles t (even regs) / t+1 (odd regs); prefetch t+2.
  bf16v8 e0, e1, e2, e3, o0, o1, o2, o3;
  LOADT(e0, e1, e2, e3, 0)
  LOADT(o0, o1, o2, o3, 1)
  for (int t = 0; t < NTIL; t += 2) {
    BODY(e0, e1, e2, e3, t)
    if (t + 2 < NTIL) LOADT(e0, e1, e2, e3, t + 2)
    BODY(o0, o1, o2, o3, t + 1)
    if (t + 3 < NTIL) LOADT(o0, o1, o2, o3, t + 3)
  }
#undef LOADT
#undef BODY
}

// ---------------------------------------------------------------------------
// k_rerank: exact fp32 dots for all candidates; exact top-9 (jax tie-break);
// certify exact-9th > TAU_LO + EPS_DOT, set fbflag=1 on success.
__global__ void k_rerank(const float* __restrict__ qn, const int* __restrict__ cnt,
                         const int* __restrict__ cand, int* __restrict__ fbflag,
                         float* __restrict__ kval, int* __restrict__ kidx) {
  int lane = threadIdx.x & 63;
  int wv   = threadIdx.x >> 6;
  int i = blockIdx.x * 4 + wv;
  int c = cnt[i];
  if (c < KTOP || c > CAP) return;         // fbflag stays 0 -> k_fb owns row
  float qi0 = qn[(size_t)i * D + lane];
  float qi1 = qn[(size_t)i * D + 64 + lane];
  float kv[KTOP]; int ki[KTOP];
#pragma unroll
  for (int t = 0; t < KTOP; ++t) { kv[t] = -INFINITY; ki[t] = 0x7fffffff; }
  int jc = cand[(size_t)i * CAP];          // prefetch candidate 0
  float b0 = qn[(size_t)jc * D + lane];
  float b1 = qn[(size_t)jc * D + 64 + lane];
  for (int t = 0; t < c; ++t) {
    int jn = (t + 1 < c) ? cand[(size_t)i * CAP + t + 1] : jc;
    float p = qi0 * b0 + qi1 * b1;
    int jcur = jc;
    jc = jn;                               // issue next row's loads now
    b0 = qn[(size_t)jn * D + lane];
    b1 = qn[(size_t)jn * D + 64 + lane];
#pragma unroll
    for (int off = 1; off < 64; off <<= 1) p += __shfl_xor(p, off);
    topk_insert<KTOP>(kv, ki, p, jcur);    // wave-uniform branch
  }
  if (kv[KTOP - 1] <= TAU_LO + EPS_DOT) return;   // cert fail -> k_fb
  if (lane == 0) {
    fbflag[i] = 1;
#pragma unroll
    for (int t = 0; t < KTOP; ++t) {
      kval[(size_t)i * KTOP + t] = kv[t];
      kidx[(size_t)i * KTOP + t] = ki[t];
    }
  }
}

// ---------------------------------------------------------------------------
// k_fb: exact fp32 full-row top-9 backstop (P ~ 1e-13 per row).
__global__ void k_fb(const float* __restrict__ qn, const int* __restrict__ fbflag,
                     float* __restrict__ kval, int* __restrict__ kidx) {
  __shared__ float qi_s[4][D];
  int lane = threadIdx.x & 63;
  int wv   = threadIdx.x >> 6;
  int i = blockIdx.x * 4 + wv;
  if (fbflag[i] == 1) return;              // rerank certified it
  qi_s[wv][lane]      = qn[(size_t)i * D + lane];
  qi_s[wv][64 + lane] = qn[(size_t)i * D + 64 + lane];
  float kv[KTOP]; int ki[KTOP];
#pragma unroll
  for (int t = 0; t < KTOP; ++t) { kv[t] = -INFINITY; ki[t] = 0x7fffffff; }
  const float4* qi4 = (const float4*)qi_s[wv];
  for (int jb = 0; jb < M; jb += 64) {
    int j = jb + lane;
    const float4* qj = (const float4*)(qn + (size_t)j * D);
    float dot = 0.f;
#pragma unroll 8
    for (int ch = 0; ch < 32; ++ch) {
      float4 a = qi4[ch], b = qj[ch];
      dot += a.x * b.x + a.y * b.y + a.z * b.z + a.w * b.w;
    }
    topk_insert<KTOP>(kv, ki, dot, j);
  }
#pragma unroll
  for (int off = 1; off < 64; off <<= 1) {
    float pv[KTOP]; int pj[KTOP];
#pragma unroll
    for (int t = 0; t < KTOP; ++t) {
      pv[t] = __shfl_xor(kv[t], off);
      pj[t] = __shfl_xor(ki[t], off);
    }
#pragma unroll
    for (int t = 0; t < KTOP; ++t) topk_insert<KTOP>(kv, ki, pv[t], pj[t]);
  }
  if (lane == 0) {
#pragma unroll
    for (int t = 0; t < KTOP; ++t) {
      kval[(size_t)i * KTOP + t] = kv[t];
      kidx[(size_t)i * KTOP + t] = ki[t];
    }
  }
}

// ---------------------------------------------------------------------------
// k3: mutual mask + softmax over <=9 entries + adapted query + normalize +
// project on normalized prototypes, scale by tao. One wave per query row.
__global__ void k3_out(const float* __restrict__ x, const float* __restrict__ kval,
                       const int* __restrict__ kidx, const float* __restrict__ protnT,
                       const float* __restrict__ taop, float* __restrict__ out) {
  __shared__ float sw[4][KTOP];
  __shared__ int   sj[4][KTOP];
  __shared__ float an[4][D];
  int lane = threadIdx.x & 63;
  int wv   = threadIdx.x >> 6;
  int i = blockIdx.x * 4 + wv;

  float v = -INFINITY; int jt = 0; bool mut = false;
  if (lane < KTOP) {
    v  = kval[(size_t)i * KTOP + lane];
    jt = kidx[(size_t)i * KTOP + lane];
    const int* oj = kidx + (size_t)jt * KTOP;
#pragma unroll
    for (int t = 0; t < KTOP; ++t) mut = mut || (oj[t] == i);
  }
  float lv = mut ? v : -INFINITY;
#pragma unroll
  for (int off = 1; off < 16; off <<= 1) lv = fmaxf(lv, __shfl_xor(lv, off));
  float wexp = mut ? expf(v - lv) : 0.f;    // self is always mutual -> z >= 1
  float z = wexp;
#pragma unroll
  for (int off = 1; off < 16; off <<= 1) z += __shfl_xor(z, off);
  if (lane < KTOP) { sw[wv][lane] = wexp / z; sj[wv][lane] = jt; }
  __syncthreads();

  float a0 = 0.f, a1 = 0.f;
#pragma unroll
  for (int t = 0; t < KTOP; ++t) {
    float wt = sw[wv][t];
    if (wt != 0.f) {
      int j = sj[wv][t];
      int xr = (j >> 7) * XROW + KSHOT + (j & 127);
      const float* qr = x + (size_t)xr * D;
      a0 += wt * qr[lane];
      a1 += wt * qr[64 + lane];
    }
  }
  float ss = a0 * a0 + a1 * a1;
#pragma unroll
  for (int off = 1; off < 64; off <<= 1) ss += __shfl_xor(ss, off);
  float rn = 1.0f / fmaxf(sqrtf(ss), EPSV);
  an[wv][lane]      = a0 * rn;
  an[wv][64 + lane] = a1 * rn;
  __syncthreads();

  float acc = 0.f;
#pragma unroll 8
  for (int d = 0; d < D; ++d) acc += an[wv][d] * protnT[d * NCLS + lane];
  out[(size_t)i * NCLS + lane] = taop[0] * acc;
}

// ---------------------------------------------------------------------------
extern "C" void kernel_launch(void* const* d_in, const int* in_sizes, int n_in,
                              void* d_out, int out_size, void* d_ws, size_t ws_size,
                              hipStream_t stream) {
  const float* x   = (const float*)d_in[0];
  const float* tao = (const float*)d_in[1];
  float* out = (float*)d_out;

  // workspace layout, ~11.8 MB total
  float* qn    = (float*)d_ws;                        // 8192*128 f32 (4 MB)
  short* qh    = (short*)(qn + (size_t)M * D);        // 2 MB bf16
  int*   cnt   = (int*)(qh + (size_t)M * D);          // 32 KB
  int*   fbflag= cnt + M;                             // 32 KB (contiguous)
  int*   cand  = fbflag + M;                          // 8192*160*4 = 5.2 MB
  float* kval  = (float*)(cand + (size_t)M * CAP);    // 8192*9
  int*   kidx  = (int*)(kval + (size_t)M * KTOP);
  float* protnT = (float*)(kidx + (size_t)M * KTOP);  // 128*64

  hipMemsetAsync(cnt, 0, 2 * (size_t)M * sizeof(int), stream);  // cnt + fbflag
  k0_proto<<<NCLS, 64, 0, stream>>>(x, protnT);
  k1_qnorm<<<M / 4, 256, 0, stream>>>(x, qn, qh);
  k2f<<<(M / 64) * SJ, 256, 0, stream>>>(qh, cnt, cand);
  k_rerank<<<M / 4, 256, 0, stream>>>(qn, cnt, cand, fbflag, kval, kidx);
  k_fb<<<M / 4, 256, 0, stream>>>(qn, fbflag, kval, kidx);
  k3_out<<<M / 4, 256, 0, stream>>>(x, kval, kidx, protnT, tao, out);
}

// Round 17
// 235.644 us; speedup vs baseline: 1.0916x; 1.0916x over previous
//
#include <hip/hip_runtime.h>
#include <hip/hip_bf16.h>
#include <math.h>

// Problem constants (N_WAY=64, K_SHOT=5, Q_QUERY=128, D_FEAT=128)
#define M     8192      // n*q query rows
#define D     128       // feature dim
#define NCLS  64        // n classes
#define KSHOT 5
#define XROW  133       // (k+q) rows per class in x
#define KTOP  9
#define EPSV  1e-8f

// Threshold filter + exact certificate (R13, proven):
//   k2f appends j with bf16-approx sim >= TAU_LO. k_rerank computes EXACT fp32
//   dots of all candidates, certifies iff exact-9th-among-candidates >
//   TAU_LO+EPS_DOT (=> true top-9 provably subset). Cert-fail P ~ 1e-13/row;
//   k_fb exact full-row backstop.
// R14 lesson: global atomicAdd candidate emission = fabric-atomic bound
//   (WRITE_SIZE 28MB of RMW line traffic, 212 GB/s == kernel duration).
//   Replaced with LDS counters + deterministic per-(row,block) segments.
#define TAU_LO  0.21f
#define EPS_DOT 0.005f
#define CAPB    24      // per-(row, j-split) segment capacity (lambda ~4.3)

// k2f: MFMA filter pass. Block = 64 i (4 waves x 16-i subs) x 512 j (SJ=16).
#define SJ    16
#define JPB   (M / SJ)      // 512 j per block
#define NTIL  (JPB / 16)    // 32 j-tiles of 16

typedef __attribute__((__ext_vector_type__(8))) short bf16v8;  // 8 bf16 = 4 VGPR
typedef __attribute__((__ext_vector_type__(4))) float f32v4;

// ---------------------------------------------------------------------------
// register-resident top-K with (value desc, index asc) tie-break, matching
// jax.lax.top_k set semantics; arrival-order independent for distinct indices.
template <int KN>
__device__ __forceinline__ void topk_insert(float (&kv)[KN], int (&ki)[KN],
                                            float v, int j) {
  if (v > kv[KN - 1] || (v == kv[KN - 1] && j < ki[KN - 1])) {
    float cv = v; int cj = j;
#pragma unroll
    for (int t = 0; t < KN; ++t) {
      bool b = (cv > kv[t]) || (cv == kv[t] && cj < ki[t]);
      float tv = kv[t]; int ti_ = ki[t];
      kv[t] = b ? cv : tv;  ki[t] = b ? cj : ti_;
      cv   = b ? tv : cv;   cj   = b ? ti_ : cj;
    }
  }
}

// ---------------------------------------------------------------------------
__global__ void k0_proto(const float* __restrict__ x, float* __restrict__ protnT) {
  int c = blockIdx.x;
  int lane = threadIdx.x;
  const float* base = x + (size_t)(c * XROW) * D;
  float a0 = 0.f, a1 = 0.f;
#pragma unroll
  for (int s = 0; s < KSHOT; ++s) {
    a0 += base[s * D + lane];
    a1 += base[s * D + 64 + lane];
  }
  a0 *= 0.2f; a1 *= 0.2f;
  float ss = a0 * a0 + a1 * a1;
#pragma unroll
  for (int off = 1; off < 64; off <<= 1) ss += __shfl_xor(ss, off);
  float rn = 1.0f / fmaxf(sqrtf(ss), EPSV);
  protnT[lane * NCLS + c]        = a0 * rn;
  protnT[(lane + 64) * NCLS + c] = a1 * rn;
}

// ---------------------------------------------------------------------------
// k1: L2-normalize query rows -> qn (f32) and qh (bf16).
__global__ void k1_qnorm(const float* __restrict__ x, float* __restrict__ qn,
                         short* __restrict__ qh) {
  int lane = threadIdx.x & 63;
  int wv = threadIdx.x >> 6;
  int r = blockIdx.x * 4 + wv;
  int xr = (r >> 7) * XROW + KSHOT + (r & 127);
  const float* src = x + (size_t)xr * D;
  float v0 = src[lane], v1 = src[64 + lane];
  float ss = v0 * v0 + v1 * v1;
#pragma unroll
  for (int off = 1; off < 64; off <<= 1) ss += __shfl_xor(ss, off);
  float rn = 1.0f / fmaxf(sqrtf(ss), EPSV);
  float q0 = v0 * rn, q1 = v1 * rn;
  qn[(size_t)r * D + lane]      = q0;
  qn[(size_t)r * D + 64 + lane] = q1;
  __hip_bfloat16 h0 = __float2bfloat16(q0);
  __hip_bfloat16 h1 = __float2bfloat16(q1);
  qh[(size_t)r * D + lane]      = *(short*)&h0;
  qh[(size_t)r * D + 64 + lane] = *(short*)&h1;
}

// ---------------------------------------------------------------------------
// k2f: bf16 MFMA + threshold filter. LDS per-row counters, deterministic
// per-(row, j-split) candidate segments, zero global atomics.
// D layout (m89-verified): i-col = lane&15, j-row = (lane>>4)*4 + reg.
__global__ __launch_bounds__(256) void
k2f(const short* __restrict__ qh, int* __restrict__ segcnt, int* __restrict__ cand) {
  __shared__ int lcnt[64];

  const int tid  = threadIdx.x;
  const int l    = tid & 63;
  const int w    = tid >> 6;
  const int ib   = blockIdx.x >> 4;        // 128 i-strips of 64
  const int js   = blockIdx.x & (SJ - 1);  // 16 j-splits
  const int i0   = ib * 64;
  const int j0s  = js * JPB;

  if (tid < 64) lcnt[tid] = 0;

  const bf16v8* qh8 = (const bf16v8*)qh;
  const int lg   = l >> 4;                 // k-group 0..3
  const int arow = l & 15;
  const int lrow = w * 16 + arow;          // local row 0..63
  const int myi  = i0 + lrow;              // this lane's i-row

  // persistent i-side B fragments: lane's i-row, 4 k-windows
  bf16v8 bh[4];
#pragma unroll
  for (int kk = 0; kk < 4; ++kk)
    bh[kk] = qh8[(size_t)myi * 16 + kk * 4 + lg];

  int* seg = cand + ((size_t)myi * SJ + js) * CAPB;   // this row's segment
  __syncthreads();

  for (int t = 0; t < NTIL; ++t) {
    const size_t jr16 = (size_t)(j0s + t * 16 + arow) * 16;
    bf16v8 ah0 = qh8[jr16 + 0 + lg];
    bf16v8 ah1 = qh8[jr16 + 4 + lg];
    bf16v8 ah2 = qh8[jr16 + 8 + lg];
    bf16v8 ah3 = qh8[jr16 + 12 + lg];
    f32v4 a0 = {0.f, 0.f, 0.f, 0.f};
    f32v4 a1 = {0.f, 0.f, 0.f, 0.f};
    a0 = __builtin_amdgcn_mfma_f32_16x16x32_bf16(ah0, bh[0], a0, 0, 0, 0);
    a1 = __builtin_amdgcn_mfma_f32_16x16x32_bf16(ah1, bh[1], a1, 0, 0, 0);
    a0 = __builtin_amdgcn_mfma_f32_16x16x32_bf16(ah2, bh[2], a0, 0, 0, 0);
    a1 = __builtin_amdgcn_mfma_f32_16x16x32_bf16(ah3, bh[3], a1, 0, 0, 0);
    f32v4 s = a0 + a1;

    const int jb = j0s + t * 16 + lg * 4;  // lane's 4 j-rows
#pragma unroll
    for (int u = 0; u < 4; ++u) {
      if (s[u] >= TAU_LO) {                // ~0.9% of values
        int slot = atomicAdd(&lcnt[lrow], 1);   // LDS atomic: on-CU, cheap
        if (slot < CAPB) seg[slot] = jb + u;
      }
    }
  }

  __syncthreads();
  if (tid < 64)                            // raw count; >CAPB means overflow
    segcnt[(size_t)(i0 + tid) * SJ + js] = lcnt[tid];
}

// ---------------------------------------------------------------------------
// k_rerank: exact fp32 dots for all candidates; exact top-9 (jax tie-break);
// certify exact-9th > TAU_LO + EPS_DOT, set fbflag=1 on success.
__global__ void k_rerank(const float* __restrict__ qn, const int* __restrict__ segcnt,
                         const int* __restrict__ cand, int* __restrict__ fbflag,
                         float* __restrict__ kval, int* __restrict__ kidx) {
  int lane = threadIdx.x & 63;
  int wv   = threadIdx.x >> 6;
  int i = blockIdx.x * 4 + wv;

  float qi0 = qn[(size_t)i * D + lane];
  float qi1 = qn[(size_t)i * D + 64 + lane];
  float kv[KTOP]; int ki[KTOP];
#pragma unroll
  for (int t = 0; t < KTOP; ++t) { kv[t] = -INFINITY; ki[t] = 0x7fffffff; }
  bool bad = false;
  for (int s = 0; s < SJ; ++s) {
    int sc = segcnt[(size_t)i * SJ + s];   // wave-uniform scalar load
    if (sc > CAPB) { bad = true; break; }
    const int* seg = cand + ((size_t)i * SJ + s) * CAPB;
    for (int t = 0; t < sc; ++t) {
      int jc = seg[t];                     // wave-uniform
      float p = qi0 * qn[(size_t)jc * D + lane] +
                qi1 * qn[(size_t)jc * D + 64 + lane];
#pragma unroll
      for (int off = 1; off < 64; off <<= 1) p += __shfl_xor(p, off);
      topk_insert<KTOP>(kv, ki, p, jc);    // wave-uniform branch
    }
  }
  if (bad || kv[KTOP - 1] <= TAU_LO + EPS_DOT) return;  // -> k_fb
  if (lane == 0) {
    fbflag[i] = 1;
#pragma unroll
    for (int t = 0; t < KTOP; ++t) {
      kval[(size_t)i * KTOP + t] = kv[t];
      kidx[(size_t)i * KTOP + t] = ki[t];
    }
  }
}

// ---------------------------------------------------------------------------
// k_fb: exact fp32 full-row top-9 backstop (P ~ 1e-13 per row).
__global__ void k_fb(const float* __restrict__ qn, const int* __restrict__ fbflag,
                     float* __restrict__ kval, int* __restrict__ kidx) {
  __shared__ float qi_s[4][D];
  int lane = threadIdx.x & 63;
  int wv   = threadIdx.x >> 6;
  int i = blockIdx.x * 4 + wv;
  if (fbflag[i] == 1) return;              // rerank certified it
  qi_s[wv][lane]      = qn[(size_t)i * D + lane];
  qi_s[wv][64 + lane] = qn[(size_t)i * D + 64 + lane];
  float kv[KTOP]; int ki[KTOP];
#pragma unroll
  for (int t = 0; t < KTOP; ++t) { kv[t] = -INFINITY; ki[t] = 0x7fffffff; }
  const float4* qi4 = (const float4*)qi_s[wv];
  for (int jb = 0; jb < M; jb += 64) {
    int j = jb + lane;
    const float4* qj = (const float4*)(qn + (size_t)j * D);
    float dot = 0.f;
#pragma unroll 8
    for (int ch = 0; ch < 32; ++ch) {
      float4 a = qi4[ch], b = qj[ch];
      dot += a.x * b.x + a.y * b.y + a.z * b.z + a.w * b.w;
    }
    topk_insert<KTOP>(kv, ki, dot, j);
  }
#pragma unroll
  for (int off = 1; off < 64; off <<= 1) {
    float pv[KTOP]; int pj[KTOP];
#pragma unroll
    for (int t = 0; t < KTOP; ++t) {
      pv[t] = __shfl_xor(kv[t], off);
      pj[t] = __shfl_xor(ki[t], off);
    }
#pragma unroll
    for (int t = 0; t < KTOP; ++t) topk_insert<KTOP>(kv, ki, pv[t], pj[t]);
  }
  if (lane == 0) {
#pragma unroll
    for (int t = 0; t < KTOP; ++t) {
      kval[(size_t)i * KTOP + t] = kv[t];
      kidx[(size_t)i * KTOP + t] = ki[t];
    }
  }
}

// ---------------------------------------------------------------------------
// k3: mutual mask + softmax over <=9 entries + adapted query + normalize +
// project on normalized prototypes, scale by tao. One wave per query row.
__global__ void k3_out(const float* __restrict__ x, const float* __restrict__ kval,
                       const int* __restrict__ kidx, const float* __restrict__ protnT,
                       const float* __restrict__ taop, float* __restrict__ out) {
  __shared__ float sw[4][KTOP];
  __shared__ int   sj[4][KTOP];
  __shared__ float an[4][D];
  int lane = threadIdx.x & 63;
  int wv   = threadIdx.x >> 6;
  int i = blockIdx.x * 4 + wv;

  float v = -INFINITY; int jt = 0; bool mut = false;
  if (lane < KTOP) {
    v  = kval[(size_t)i * KTOP + lane];
    jt = kidx[(size_t)i * KTOP + lane];
    const int* oj = kidx + (size_t)jt * KTOP;
#pragma unroll
    for (int t = 0; t < KTOP; ++t) mut = mut || (oj[t] == i);
  }
  float lv = mut ? v : -INFINITY;
#pragma unroll
  for (int off = 1; off < 16; off <<= 1) lv = fmaxf(lv, __shfl_xor(lv, off));
  float wexp = mut ? expf(v - lv) : 0.f;    // self is always mutual -> z >= 1
  float z = wexp;
#pragma unroll
  for (int off = 1; off < 16; off <<= 1) z += __shfl_xor(z, off);
  if (lane < KTOP) { sw[wv][lane] = wexp / z; sj[wv][lane] = jt; }
  __syncthreads();

  float a0 = 0.f, a1 = 0.f;
#pragma unroll
  for (int t = 0; t < KTOP; ++t) {
    float wt = sw[wv][t];
    if (wt != 0.f) {
      int j = sj[wv][t];
      int xr = (j >> 7) * XROW + KSHOT + (j & 127);
      const float* qr = x + (size_t)xr * D;
      a0 += wt * qr[lane];
      a1 += wt * qr[64 + lane];
    }
  }
  float ss = a0 * a0 + a1 * a1;
#pragma unroll
  for (int off = 1; off < 64; off <<= 1) ss += __shfl_xor(ss, off);
  float rn = 1.0f / fmaxf(sqrtf(ss), EPSV);
  an[wv][lane]      = a0 * rn;
  an[wv][64 + lane] = a1 * rn;
  __syncthreads();

  float acc = 0.f;
#pragma unroll 8
  for (int d = 0; d < D; ++d) acc += an[wv][d] * protnT[d * NCLS + lane];
  out[(size_t)i * NCLS + lane] = taop[0] * acc;
}

// ---------------------------------------------------------------------------
extern "C" void kernel_launch(void* const* d_in, const int* in_sizes, int n_in,
                              void* d_out, int out_size, void* d_ws, size_t ws_size,
                              hipStream_t stream) {
  const float* x   = (const float*)d_in[0];
  const float* tao = (const float*)d_in[1];
  float* out = (float*)d_out;

  // workspace layout, ~19.5 MB total
  float* qn     = (float*)d_ws;                       // 8192*128 f32 (4 MB)
  short* qh     = (short*)(qn + (size_t)M * D);       // 2 MB bf16
  int*   fbflag = (int*)(qh + (size_t)M * D);         // 32 KB
  int*   segcnt = fbflag + M;                         // 8192*16 = 512 KB
  int*   cand   = segcnt + (size_t)M * SJ;            // 8192*16*24*4 = 12.6 MB
  float* kval   = (float*)(cand + (size_t)M * SJ * CAPB);  // 8192*9
  int*   kidx   = (int*)(kval + (size_t)M * KTOP);
  float* protnT = (float*)(kidx + (size_t)M * KTOP);  // 128*64

  hipMemsetAsync(fbflag, 0, (size_t)M * sizeof(int), stream);
  k0_proto<<<NCLS, 64, 0, stream>>>(x, protnT);
  k1_qnorm<<<M / 4, 256, 0, stream>>>(x, qn, qh);
  k2f<<<(M / 64) * SJ, 256, 0, stream>>>(qh, segcnt, cand);
  k_rerank<<<M / 4, 256, 0, stream>>>(qn, segcnt, cand, fbflag, kval, kidx);
  k_fb<<<M / 4, 256, 0, stream>>>(qn, fbflag, kval, kidx);
  k3_out<<<M / 4, 256, 0, stream>>>(x, kval, kidx, protnT, tao, out);
}

// Round 18
// 149.287 us; speedup vs baseline: 1.7230x; 1.5785x over previous
//
#include <hip/hip_runtime.h>
#include <hip/hip_bf16.h>
#include <math.h>

// Problem constants (N_WAY=64, K_SHOT=5, Q_QUERY=128, D_FEAT=128)
#define M     8192      // n*q query rows
#define D     128       // feature dim
#define NCLS  64        // n classes
#define KSHOT 5
#define XROW  133       // (k+q) rows per class in x
#define KTOP  9
#define EPSV  1e-8f

// Threshold filter + exact certificate (R13, proven):
//   k2f appends j with bf16-approx sim >= TAU_LO. k_rr computes EXACT fp32
//   dots of all candidates, certifies iff exact-9th-among-candidates >
//   TAU_LO+EPS_DOT (=> true top-9 provably subset); else inline exact
//   full-row fallback (P ~ 1e-13/row).
// R14 lesson: global-atomic emission = fabric-bound. R16: LDS counters +
//   deterministic per-(row,j-split) segments. R16 lesson: direct-global
//   A-frag loads scatter over 16 cache lines/instr -> TA/L2-request bound
//   (1340 cyc/iter, all pipes <9%). R17: back to LDS-staged tiles (R12's
//   3x-faster structure) + segment emission.
#define TAU_LO  0.21f
#define EPS_DOT 0.005f
#define CAPB    24      // per-(row, j-split) segment capacity (lambda ~4.3)

// k2f: MFMA filter pass. Block = 64 i (4 waves x 16-i subs) x 512 j (SJ=16).
#define SJ    16
#define JPB   (M / SJ)      // 512 j per block
#define NTIL  (JPB / 16)    // 32 j-tiles of 16

typedef __attribute__((__ext_vector_type__(8))) short bf16v8;  // 8 bf16 = 4 VGPR
typedef __attribute__((__ext_vector_type__(4))) float f32v4;

// ---------------------------------------------------------------------------
// register-resident top-K with (value desc, index asc) tie-break, matching
// jax.lax.top_k set semantics; arrival-order independent for distinct indices.
template <int KN>
__device__ __forceinline__ void topk_insert(float (&kv)[KN], int (&ki)[KN],
                                            float v, int j) {
  if (v > kv[KN - 1] || (v == kv[KN - 1] && j < ki[KN - 1])) {
    float cv = v; int cj = j;
#pragma unroll
    for (int t = 0; t < KN; ++t) {
      bool b = (cv > kv[t]) || (cv == kv[t] && cj < ki[t]);
      float tv = kv[t]; int ti_ = ki[t];
      kv[t] = b ? cv : tv;  ki[t] = b ? cj : ti_;
      cv   = b ? tv : cv;   cj   = b ? ti_ : cj;
    }
  }
}

// ---------------------------------------------------------------------------
__global__ void k0_proto(const float* __restrict__ x, float* __restrict__ protnT) {
  int c = blockIdx.x;
  int lane = threadIdx.x;
  const float* base = x + (size_t)(c * XROW) * D;
  float a0 = 0.f, a1 = 0.f;
#pragma unroll
  for (int s = 0; s < KSHOT; ++s) {
    a0 += base[s * D + lane];
    a1 += base[s * D + 64 + lane];
  }
  a0 *= 0.2f; a1 *= 0.2f;
  float ss = a0 * a0 + a1 * a1;
#pragma unroll
  for (int off = 1; off < 64; off <<= 1) ss += __shfl_xor(ss, off);
  float rn = 1.0f / fmaxf(sqrtf(ss), EPSV);
  protnT[lane * NCLS + c]        = a0 * rn;
  protnT[(lane + 64) * NCLS + c] = a1 * rn;
}

// ---------------------------------------------------------------------------
// k1: L2-normalize query rows -> qn (f32) and qh (bf16).
__global__ void k1_qnorm(const float* __restrict__ x, float* __restrict__ qn,
                         short* __restrict__ qh) {
  int lane = threadIdx.x & 63;
  int wv = threadIdx.x >> 6;
  int r = blockIdx.x * 4 + wv;
  int xr = (r >> 7) * XROW + KSHOT + (r & 127);
  const float* src = x + (size_t)xr * D;
  float v0 = src[lane], v1 = src[64 + lane];
  float ss = v0 * v0 + v1 * v1;
#pragma unroll
  for (int off = 1; off < 64; off <<= 1) ss += __shfl_xor(ss, off);
  float rn = 1.0f / fmaxf(sqrtf(ss), EPSV);
  float q0 = v0 * rn, q1 = v1 * rn;
  qn[(size_t)r * D + lane]      = q0;
  qn[(size_t)r * D + 64 + lane] = q1;
  __hip_bfloat16 h0 = __float2bfloat16(q0);
  __hip_bfloat16 h1 = __float2bfloat16(q1);
  qh[(size_t)r * D + lane]      = *(short*)&h0;
  qh[(size_t)r * D + 64 + lane] = *(short*)&h1;
}

// ---------------------------------------------------------------------------
// k2f: bf16 MFMA + threshold filter. LDS-staged double-buffered j-tile
// (1 barrier/tile, 2-ahead reg prefetch, XOR-swizzled slots), LDS per-row
// counters, deterministic per-(row, j-split) segments, zero global atomics.
// D layout (m89-verified): i-col = lane&15, j-row = (lane>>4)*4 + reg.
__global__ __launch_bounds__(256) void
k2f(const short* __restrict__ qh, int* __restrict__ segcnt, int* __restrict__ cand) {
  __shared__ __align__(16) short jh[2][16 * D];   // 2 x 4 KB j-tile
  __shared__ int lcnt[64];

  const int tid  = threadIdx.x;
  const int l    = tid & 63;
  const int w    = tid >> 6;
  const int ib   = blockIdx.x >> 4;        // 128 i-strips of 64
  const int js   = blockIdx.x & (SJ - 1);  // 16 j-splits
  const int i0   = ib * 64;
  const int j0s  = js * JPB;

  if (tid < 64) lcnt[tid] = 0;

  const bf16v8* qh8 = (const bf16v8*)qh;
  const int lg   = l >> 4;                 // k-group 0..3
  const int arow = l & 15;
  const int lrow = w * 16 + arow;          // local row 0..63
  const int myi  = i0 + lrow;              // this lane's i-row

  // persistent i-side B fragments: lane's i-row, 4 k-windows
  bf16v8 bh[4];
#pragma unroll
  for (int kk = 0; kk < 4; ++kk)
    bh[kk] = qh8[(size_t)myi * 16 + kk * 4 + lg];

  // staging: thread -> (row, chunk), XOR-swizzled slot (conflict-free reads)
  const int srow = tid >> 4;               // 0..15
  const int schk = tid & 15;               // 0..15
  const int sslot = srow * 16 + (schk ^ (srow & 7));
  int rslot[4];
#pragma unroll
  for (int kk = 0; kk < 4; ++kk)
    rslot[kk] = arow * 16 + ((kk * 4 + lg) ^ (arow & 7));

  int* seg = cand + ((size_t)myi * SJ + js) * CAPB;   // this row's segment

  // prologue: tile 0 -> buf0; prefetch tile 1 to regs
  bf16v8 sa = qh8[(size_t)(j0s + srow) * 16 + schk];
  ((bf16v8*)jh[0])[sslot] = sa;
  sa = qh8[(size_t)(j0s + 16 + srow) * 16 + schk];
  __syncthreads();                         // covers lcnt init + buf0

  for (int t = 0; t < NTIL; ++t) {
    // write next tile into other buffer (its readers done at barrier of t-1),
    // then prefetch t+2 from global (latency hides under this tile's compute)
    if (t + 1 < NTIL) {
      ((bf16v8*)jh[(t + 1) & 1])[sslot] = sa;
      if (t + 2 < NTIL)
        sa = qh8[(size_t)(j0s + (t + 2) * 16 + srow) * 16 + schk];
    }

    const bf16v8* H = (const bf16v8*)jh[t & 1];
    f32v4 a0 = {0.f, 0.f, 0.f, 0.f};
    f32v4 a1 = {0.f, 0.f, 0.f, 0.f};
    a0 = __builtin_amdgcn_mfma_f32_16x16x32_bf16(H[rslot[0]], bh[0], a0, 0, 0, 0);
    a1 = __builtin_amdgcn_mfma_f32_16x16x32_bf16(H[rslot[1]], bh[1], a1, 0, 0, 0);
    a0 = __builtin_amdgcn_mfma_f32_16x16x32_bf16(H[rslot[2]], bh[2], a0, 0, 0, 0);
    a1 = __builtin_amdgcn_mfma_f32_16x16x32_bf16(H[rslot[3]], bh[3], a1, 0, 0, 0);
    f32v4 s = a0 + a1;

    const int jb = j0s + t * 16 + lg * 4;  // lane's 4 j-rows
#pragma unroll
    for (int u = 0; u < 4; ++u) {
      if (s[u] >= TAU_LO) {                // ~0.9% of values
        int slot = atomicAdd(&lcnt[lrow], 1);   // LDS atomic: on-CU, cheap
        if (slot < CAPB) seg[slot] = jb + u;
      }
    }

    __syncthreads();   // readers of buf[t&1] done; writes to buf[(t+1)&1] visible
  }

  if (tid < 64)                            // raw count; >CAPB means overflow
    segcnt[(size_t)(i0 + tid) * SJ + js] = lcnt[tid];
}

// ---------------------------------------------------------------------------
// k_rr: exact fp32 dots for all candidates; exact top-9 (jax tie-break);
// certify exact-9th > TAU_LO + EPS_DOT. Uncertified rows (P ~ 1e-13) run the
// inline exact full-row fallback. Every row writes its result every call.
__global__ void k_rr(const float* __restrict__ qn, const int* __restrict__ segcnt,
                     const int* __restrict__ cand,
                     float* __restrict__ kval, int* __restrict__ kidx) {
  __shared__ float qi_s[4][D];
  int lane = threadIdx.x & 63;
  int wv   = threadIdx.x >> 6;
  int i = blockIdx.x * 4 + wv;

  float qi0 = qn[(size_t)i * D + lane];
  float qi1 = qn[(size_t)i * D + 64 + lane];
  float kv[KTOP]; int ki[KTOP];
#pragma unroll
  for (int t = 0; t < KTOP; ++t) { kv[t] = -INFINITY; ki[t] = 0x7fffffff; }
  bool bad = false;
  for (int s = 0; s < SJ; ++s) {
    int sc = segcnt[(size_t)i * SJ + s];   // wave-uniform scalar load
    if (sc > CAPB) { bad = true; break; }
    const int* seg = cand + ((size_t)i * SJ + s) * CAPB;
    for (int t = 0; t < sc; ++t) {
      int jc = seg[t];                     // wave-uniform
      float p = qi0 * qn[(size_t)jc * D + lane] +
                qi1 * qn[(size_t)jc * D + 64 + lane];
#pragma unroll
      for (int off = 1; off < 64; off <<= 1) p += __shfl_xor(p, off);
      topk_insert<KTOP>(kv, ki, p, jc);    // wave-uniform branch
    }
  }

  // certificate (wave-uniform: kv identical across lanes)
  if (bad || kv[KTOP - 1] <= TAU_LO + EPS_DOT) {
    // inline exact full-row fallback (no barrier; only this wave's LDS slice)
    qi_s[wv][lane]      = qi0;
    qi_s[wv][64 + lane] = qi1;
#pragma unroll
    for (int t = 0; t < KTOP; ++t) { kv[t] = -INFINITY; ki[t] = 0x7fffffff; }
    const float4* qi4 = (const float4*)qi_s[wv];
    for (int jb = 0; jb < M; jb += 64) {
      int j = jb + lane;
      const float4* qj = (const float4*)(qn + (size_t)j * D);
      float dot = 0.f;
#pragma unroll 8
      for (int ch = 0; ch < 32; ++ch) {
        float4 a = qi4[ch], b = qj[ch];
        dot += a.x * b.x + a.y * b.y + a.z * b.z + a.w * b.w;
      }
      topk_insert<KTOP>(kv, ki, dot, j);
    }
#pragma unroll
    for (int off = 1; off < 64; off <<= 1) {
      float pv[KTOP]; int pj[KTOP];
#pragma unroll
      for (int t = 0; t < KTOP; ++t) {
        pv[t] = __shfl_xor(kv[t], off);
        pj[t] = __shfl_xor(ki[t], off);
      }
#pragma unroll
      for (int t = 0; t < KTOP; ++t) topk_insert<KTOP>(kv, ki, pv[t], pj[t]);
    }
  }

  if (lane == 0) {
#pragma unroll
    for (int t = 0; t < KTOP; ++t) {
      kval[(size_t)i * KTOP + t] = kv[t];
      kidx[(size_t)i * KTOP + t] = ki[t];
    }
  }
}

// ---------------------------------------------------------------------------
// k3: mutual mask + softmax over <=9 entries + adapted query + normalize +
// project on normalized prototypes, scale by tao. One wave per query row.
__global__ void k3_out(const float* __restrict__ x, const float* __restrict__ kval,
                       const int* __restrict__ kidx, const float* __restrict__ protnT,
                       const float* __restrict__ taop, float* __restrict__ out) {
  __shared__ float sw[4][KTOP];
  __shared__ int   sj[4][KTOP];
  __shared__ float an[4][D];
  int lane = threadIdx.x & 63;
  int wv   = threadIdx.x >> 6;
  int i = blockIdx.x * 4 + wv;

  float v = -INFINITY; int jt = 0; bool mut = false;
  if (lane < KTOP) {
    v  = kval[(size_t)i * KTOP + lane];
    jt = kidx[(size_t)i * KTOP + lane];
    const int* oj = kidx + (size_t)jt * KTOP;
#pragma unroll
    for (int t = 0; t < KTOP; ++t) mut = mut || (oj[t] == i);
  }
  float lv = mut ? v : -INFINITY;
#pragma unroll
  for (int off = 1; off < 16; off <<= 1) lv = fmaxf(lv, __shfl_xor(lv, off));
  float wexp = mut ? expf(v - lv) : 0.f;    // self is always mutual -> z >= 1
  float z = wexp;
#pragma unroll
  for (int off = 1; off < 16; off <<= 1) z += __shfl_xor(z, off);
  if (lane < KTOP) { sw[wv][lane] = wexp / z; sj[wv][lane] = jt; }
  __syncthreads();

  float a0 = 0.f, a1 = 0.f;
#pragma unroll
  for (int t = 0; t < KTOP; ++t) {
    float wt = sw[wv][t];
    if (wt != 0.f) {
      int j = sj[wv][t];
      int xr = (j >> 7) * XROW + KSHOT + (j & 127);
      const float* qr = x + (size_t)xr * D;
      a0 += wt * qr[lane];
      a1 += wt * qr[64 + lane];
    }
  }
  float ss = a0 * a0 + a1 * a1;
#pragma unroll
  for (int off = 1; off < 64; off <<= 1) ss += __shfl_xor(ss, off);
  float rn = 1.0f / fmaxf(sqrtf(ss), EPSV);
  an[wv][lane]      = a0 * rn;
  an[wv][64 + lane] = a1 * rn;
  __syncthreads();

  float acc = 0.f;
#pragma unroll 8
  for (int d = 0; d < D; ++d) acc += an[wv][d] * protnT[d * NCLS + lane];
  out[(size_t)i * NCLS + lane] = taop[0] * acc;
}

// ---------------------------------------------------------------------------
extern "C" void kernel_launch(void* const* d_in, const int* in_sizes, int n_in,
                              void* d_out, int out_size, void* d_ws, size_t ws_size,
                              hipStream_t stream) {
  const float* x   = (const float*)d_in[0];
  const float* tao = (const float*)d_in[1];
  float* out = (float*)d_out;

  // workspace layout, ~19.5 MB total
  float* qn     = (float*)d_ws;                       // 8192*128 f32 (4 MB)
  short* qh     = (short*)(qn + (size_t)M * D);       // 2 MB bf16
  int*   segcnt = (int*)(qh + (size_t)M * D);         // 8192*16 = 512 KB
  int*   cand   = segcnt + (size_t)M * SJ;            // 8192*16*24*4 = 12.6 MB
  float* kval   = (float*)(cand + (size_t)M * SJ * CAPB);  // 8192*9
  int*   kidx   = (int*)(kval + (size_t)M * KTOP);
  float* protnT = (float*)(kidx + (size_t)M * KTOP);  // 128*64

  k0_proto<<<NCLS, 64, 0, stream>>>(x, protnT);
  k1_qnorm<<<M / 4, 256, 0, stream>>>(x, qn, qh);
  k2f<<<(M / 64) * SJ, 256, 0, stream>>>(qh, segcnt, cand);
  k_rr<<<M / 4, 256, 0, stream>>>(qn, segcnt, cand, kval, kidx);
  k3_out<<<M / 4, 256, 0, stream>>>(x, kval, kidx, protnT, tao, out);
}

// Round 19
// 146.112 us; speedup vs baseline: 1.7604x; 1.0217x over previous
//
#include <hip/hip_runtime.h>
#include <hip/hip_bf16.h>
#include <math.h>

// Problem constants (N_WAY=64, K_SHOT=5, Q_QUERY=128, D_FEAT=128)
#define M     8192      // n*q query rows
#define D     128       // feature dim
#define NCLS  64        // n classes
#define KSHOT 5
#define XROW  133       // (k+q) rows per class in x
#define KTOP  9
#define EPSV  1e-8f

// Threshold filter + exact certificate (R13) + packed-value selection (R18):
//   k2f packs (bf16(v)<<16 | j) for v >= TAU_LO into per-(row,j-split)
//   segments (R16 LDS-counter emission, zero global atomics). k_rr selects
//   top-9 by STORED value lane-parallel, exact-re-dots only entries with
//   stored >= v9s - 2*EPS_STORE (provably a superset of the exact top-9),
//   then certifies exact-9th > TAU_LO + EPS_DOT. Fallback P ~ 1e-13/row.
// R17 lesson: serial per-candidate re-dot chain (jc->qn->butterfly) made
//   k_rr 91us; select-by-stored cuts re-dots ~5x and loads lane-parallel.
#define TAU_LO    0.21f
#define EPS_DOT   0.005f
#define EPS_STORE 0.008f    // mfma err 0.004 + bf16 truncation 0.004
#define CAPB      24        // per-(row, j-split) segment capacity (lambda ~4.3)

// k2f: MFMA filter pass. Block = 64 i (4 waves x 16-i subs) x 512 j (SJ=16).
#define SJ    16
#define JPB   (M / SJ)      // 512 j per block
#define NTIL  (JPB / 16)    // 32 j-tiles of 16
#define NRND  6             // max pair rounds in k_rr (16*24/64 = 6)

typedef __attribute__((__ext_vector_type__(8))) short bf16v8;  // 8 bf16 = 4 VGPR
typedef __attribute__((__ext_vector_type__(4))) float f32v4;

// ---------------------------------------------------------------------------
// register-resident top-K with (value desc, index asc) tie-break, matching
// jax.lax.top_k set semantics; arrival-order independent for distinct indices.
template <int KN>
__device__ __forceinline__ void topk_insert(float (&kv)[KN], int (&ki)[KN],
                                            float v, int j) {
  if (v > kv[KN - 1] || (v == kv[KN - 1] && j < ki[KN - 1])) {
    float cv = v; int cj = j;
#pragma unroll
    for (int t = 0; t < KN; ++t) {
      bool b = (cv > kv[t]) || (cv == kv[t] && cj < ki[t]);
      float tv = kv[t]; int ti_ = ki[t];
      kv[t] = b ? cv : tv;  ki[t] = b ? cj : ti_;
      cv   = b ? tv : cv;   cj   = b ? ti_ : cj;
    }
  }
}

// ---------------------------------------------------------------------------
__global__ void k0_proto(const float* __restrict__ x, float* __restrict__ protnT) {
  int c = blockIdx.x;
  int lane = threadIdx.x;
  const float* base = x + (size_t)(c * XROW) * D;
  float a0 = 0.f, a1 = 0.f;
#pragma unroll
  for (int s = 0; s < KSHOT; ++s) {
    a0 += base[s * D + lane];
    a1 += base[s * D + 64 + lane];
  }
  a0 *= 0.2f; a1 *= 0.2f;
  float ss = a0 * a0 + a1 * a1;
#pragma unroll
  for (int off = 1; off < 64; off <<= 1) ss += __shfl_xor(ss, off);
  float rn = 1.0f / fmaxf(sqrtf(ss), EPSV);
  protnT[lane * NCLS + c]        = a0 * rn;
  protnT[(lane + 64) * NCLS + c] = a1 * rn;
}

// ---------------------------------------------------------------------------
// k1: L2-normalize query rows -> qn (f32) and qh (bf16).
__global__ void k1_qnorm(const float* __restrict__ x, float* __restrict__ qn,
                         short* __restrict__ qh) {
  int lane = threadIdx.x & 63;
  int wv = threadIdx.x >> 6;
  int r = blockIdx.x * 4 + wv;
  int xr = (r >> 7) * XROW + KSHOT + (r & 127);
  const float* src = x + (size_t)xr * D;
  float v0 = src[lane], v1 = src[64 + lane];
  float ss = v0 * v0 + v1 * v1;
#pragma unroll
  for (int off = 1; off < 64; off <<= 1) ss += __shfl_xor(ss, off);
  float rn = 1.0f / fmaxf(sqrtf(ss), EPSV);
  float q0 = v0 * rn, q1 = v1 * rn;
  qn[(size_t)r * D + lane]      = q0;
  qn[(size_t)r * D + 64 + lane] = q1;
  __hip_bfloat16 h0 = __float2bfloat16(q0);
  __hip_bfloat16 h1 = __float2bfloat16(q1);
  qh[(size_t)r * D + lane]      = *(short*)&h0;
  qh[(size_t)r * D + 64 + lane] = *(short*)&h1;
}

// ---------------------------------------------------------------------------
// k2f: bf16 MFMA + threshold filter. LDS-staged double-buffered j-tile,
// LDS per-row counters, per-(row, j-split) segments of packed (bf16(v)<<16|j).
// D layout (m89-verified): i-col = lane&15, j-row = (lane>>4)*4 + reg.
__global__ __launch_bounds__(256) void
k2f(const short* __restrict__ qh, int* __restrict__ segcnt,
    unsigned* __restrict__ cand) {
  __shared__ __align__(16) short jh[2][16 * D];   // 2 x 4 KB j-tile
  __shared__ int lcnt[64];

  const int tid  = threadIdx.x;
  const int l    = tid & 63;
  const int w    = tid >> 6;
  const int ib   = blockIdx.x >> 4;        // 128 i-strips of 64
  const int js   = blockIdx.x & (SJ - 1);  // 16 j-splits
  const int i0   = ib * 64;
  const int j0s  = js * JPB;

  if (tid < 64) lcnt[tid] = 0;

  const bf16v8* qh8 = (const bf16v8*)qh;
  const int lg   = l >> 4;                 // k-group 0..3
  const int arow = l & 15;
  const int lrow = w * 16 + arow;          // local row 0..63
  const int myi  = i0 + lrow;              // this lane's i-row

  bf16v8 bh[4];
#pragma unroll
  for (int kk = 0; kk < 4; ++kk)
    bh[kk] = qh8[(size_t)myi * 16 + kk * 4 + lg];

  const int srow = tid >> 4;
  const int schk = tid & 15;
  const int sslot = srow * 16 + (schk ^ (srow & 7));
  int rslot[4];
#pragma unroll
  for (int kk = 0; kk < 4; ++kk)
    rslot[kk] = arow * 16 + ((kk * 4 + lg) ^ (arow & 7));

  unsigned* seg = cand + ((size_t)myi * SJ + js) * CAPB;

  bf16v8 sa = qh8[(size_t)(j0s + srow) * 16 + schk];
  ((bf16v8*)jh[0])[sslot] = sa;
  sa = qh8[(size_t)(j0s + 16 + srow) * 16 + schk];
  __syncthreads();                         // covers lcnt init + buf0

  for (int t = 0; t < NTIL; ++t) {
    if (t + 1 < NTIL) {
      ((bf16v8*)jh[(t + 1) & 1])[sslot] = sa;
      if (t + 2 < NTIL)
        sa = qh8[(size_t)(j0s + (t + 2) * 16 + srow) * 16 + schk];
    }

    const bf16v8* H = (const bf16v8*)jh[t & 1];
    f32v4 a0 = {0.f, 0.f, 0.f, 0.f};
    f32v4 a1 = {0.f, 0.f, 0.f, 0.f};
    a0 = __builtin_amdgcn_mfma_f32_16x16x32_bf16(H[rslot[0]], bh[0], a0, 0, 0, 0);
    a1 = __builtin_amdgcn_mfma_f32_16x16x32_bf16(H[rslot[1]], bh[1], a1, 0, 0, 0);
    a0 = __builtin_amdgcn_mfma_f32_16x16x32_bf16(H[rslot[2]], bh[2], a0, 0, 0, 0);
    a1 = __builtin_amdgcn_mfma_f32_16x16x32_bf16(H[rslot[3]], bh[3], a1, 0, 0, 0);
    f32v4 s = a0 + a1;

    const int jb = j0s + t * 16 + lg * 4;
#pragma unroll
    for (int u = 0; u < 4; ++u) {
      if (s[u] >= TAU_LO) {                // ~0.9% of values
        int slot = atomicAdd(&lcnt[lrow], 1);   // LDS atomic
        if (slot < CAPB)
          seg[slot] = (__float_as_uint(s[u]) & 0xFFFF0000u) | (unsigned)(jb + u);
      }
    }

    __syncthreads();
  }

  if (tid < 64)
    segcnt[(size_t)(i0 + tid) * SJ + js] = lcnt[tid];
}

// ---------------------------------------------------------------------------
// k_rr v2: lane-parallel pair load -> top-9 by stored value -> exact re-dot
// of stored >= v9s - 2*EPS_STORE (provable superset of exact top-9) ->
// certificate; inline exact full-row fallback for the P~1e-13 residue.
__global__ void k_rr(const float* __restrict__ qn, const int* __restrict__ segcnt,
                     const unsigned* __restrict__ cand,
                     float* __restrict__ kval, int* __restrict__ kidx) {
  __shared__ float qi_s[4][D];
  int lane = threadIdx.x & 63;
  int wv   = threadIdx.x >> 6;
  int i = blockIdx.x * 4 + wv;

  float qi0 = qn[(size_t)i * D + lane];
  float qi1 = qn[(size_t)i * D + 64 + lane];

  // --- segment counts + prefix scan (lanes 0..15) ---
  int sc = (lane < SJ) ? segcnt[(size_t)i * SJ + lane] : 0;
  bool bad = __any(lane < SJ && sc > CAPB);
  int pre = sc;
#pragma unroll
  for (int off = 1; off < 16; off <<= 1) {
    int o = __shfl_up(pre, off, 16);
    if ((lane & 15) >= off) pre += o;
  }
  int b[SJ];                               // inclusive prefix, all lanes
#pragma unroll
  for (int k = 0; k < SJ; ++k) b[k] = __shfl(pre, k);
  const int ct = b[SJ - 1];
  bad = bad || (ct < KTOP);

  // --- lane-parallel packed-pair load (6 predicated rounds) ---
  const unsigned* crow = cand + (size_t)i * SJ * CAPB;
  float vv[NRND]; int jj[NRND];
  float kv[KTOP]; int ki[KTOP];
#pragma unroll
  for (int t = 0; t < KTOP; ++t) { kv[t] = -INFINITY; ki[t] = 0x7fffffff; }
#pragma unroll
  for (int r = 0; r < NRND; ++r) {
    int t = r * 64 + lane;
    bool valid = t < ct;
    int s = 0, off = 0;
#pragma unroll
    for (int k = 0; k < SJ; ++k) {         // b nondecreasing -> cmov scan
      bool ge = t >= b[k];
      s   = ge ? k + 1 : s;
      off = ge ? b[k] : off;
    }
    unsigned u = valid ? crow[s * CAPB + (t - off)] : 0u;
    vv[r] = __uint_as_float(u & 0xFFFF0000u);   // exact bf16 payload
    jj[r] = (int)(u & 8191u);
    if (valid) topk_insert<KTOP>(kv, ki, vv[r], jj[r]);
  }

  // --- butterfly merge -> wave top-9 by stored value ---
#pragma unroll
  for (int off = 1; off < 64; off <<= 1) {
    float pv[KTOP]; int pj[KTOP];
#pragma unroll
    for (int t = 0; t < KTOP; ++t) {
      pv[t] = __shfl_xor(kv[t], off);
      pj[t] = __shfl_xor(ki[t], off);
    }
#pragma unroll
    for (int t = 0; t < KTOP; ++t) topk_insert<KTOP>(kv, ki, pv[t], pj[t]);
  }
  const float th = kv[KTOP - 1] - 2.0f * EPS_STORE;   // wave-uniform

  // --- exact re-dot of the borderline set (~13/row) ---
#pragma unroll
  for (int t = 0; t < KTOP; ++t) { kv[t] = -INFINITY; ki[t] = 0x7fffffff; }
  if (!bad) {
#pragma unroll
    for (int r = 0; r < NRND; ++r) {
      unsigned long long mask = __ballot(vv[r] >= th);   // invalids are 0 < th
      while (mask) {
        int bl = (int)__ffsll((long long)mask) - 1;
        mask &= mask - 1;
        int jc = __shfl(jj[r], bl);        // wave-uniform
        float p = qi0 * qn[(size_t)jc * D + lane] +
                  qi1 * qn[(size_t)jc * D + 64 + lane];
#pragma unroll
        for (int off = 1; off < 64; off <<= 1) p += __shfl_xor(p, off);
        topk_insert<KTOP>(kv, ki, p, jc);
      }
    }
  }

  // --- certificate; else inline exact full-row fallback ---
  if (bad || kv[KTOP - 1] <= TAU_LO + EPS_DOT) {
    qi_s[wv][lane]      = qi0;
    qi_s[wv][64 + lane] = qi1;
#pragma unroll
    for (int t = 0; t < KTOP; ++t) { kv[t] = -INFINITY; ki[t] = 0x7fffffff; }
    const float4* qi4 = (const float4*)qi_s[wv];
    for (int jb = 0; jb < M; jb += 64) {
      int j = jb + lane;
      const float4* qj = (const float4*)(qn + (size_t)j * D);
      float dot = 0.f;
#pragma unroll 8
      for (int ch = 0; ch < 32; ++ch) {
        float4 a = qi4[ch], bq = qj[ch];
        dot += a.x * bq.x + a.y * bq.y + a.z * bq.z + a.w * bq.w;
      }
      topk_insert<KTOP>(kv, ki, dot, j);
    }
#pragma unroll
    for (int off = 1; off < 64; off <<= 1) {
      float pv[KTOP]; int pj[KTOP];
#pragma unroll
      for (int t = 0; t < KTOP; ++t) {
        pv[t] = __shfl_xor(kv[t], off);
        pj[t] = __shfl_xor(ki[t], off);
      }
#pragma unroll
      for (int t = 0; t < KTOP; ++t) topk_insert<KTOP>(kv, ki, pv[t], pj[t]);
    }
  }

  if (lane == 0) {
#pragma unroll
    for (int t = 0; t < KTOP; ++t) {
      kval[(size_t)i * KTOP + t] = kv[t];
      kidx[(size_t)i * KTOP + t] = ki[t];
    }
  }
}

// ---------------------------------------------------------------------------
// k3: mutual mask + softmax over <=9 entries + adapted query + normalize +
// project on normalized prototypes, scale by tao. One wave per query row.
__global__ void k3_out(const float* __restrict__ x, const float* __restrict__ kval,
                       const int* __restrict__ kidx, const float* __restrict__ protnT,
                       const float* __restrict__ taop, float* __restrict__ out) {
  __shared__ float sw[4][KTOP];
  __shared__ int   sj[4][KTOP];
  __shared__ float an[4][D];
  int lane = threadIdx.x & 63;
  int wv   = threadIdx.x >> 6;
  int i = blockIdx.x * 4 + wv;

  float v = -INFINITY; int jt = 0; bool mut = false;
  if (lane < KTOP) {
    v  = kval[(size_t)i * KTOP + lane];
    jt = kidx[(size_t)i * KTOP + lane];
    const int* oj = kidx + (size_t)jt * KTOP;
#pragma unroll
    for (int t = 0; t < KTOP; ++t) mut = mut || (oj[t] == i);
  }
  float lv = mut ? v : -INFINITY;
#pragma unroll
  for (int off = 1; off < 16; off <<= 1) lv = fmaxf(lv, __shfl_xor(lv, off));
  float wexp = mut ? expf(v - lv) : 0.f;    // self is always mutual -> z >= 1
  float z = wexp;
#pragma unroll
  for (int off = 1; off < 16; off <<= 1) z += __shfl_xor(z, off);
  if (lane < KTOP) { sw[wv][lane] = wexp / z; sj[wv][lane] = jt; }
  __syncthreads();

  float a0 = 0.f, a1 = 0.f;
#pragma unroll
  for (int t = 0; t < KTOP; ++t) {
    float wt = sw[wv][t];
    if (wt != 0.f) {
      int j = sj[wv][t];
      int xr = (j >> 7) * XROW + KSHOT + (j & 127);
      const float* qr = x + (size_t)xr * D;
      a0 += wt * qr[lane];
      a1 += wt * qr[64 + lane];
    }
  }
  float ss = a0 * a0 + a1 * a1;
#pragma unroll
  for (int off = 1; off < 64; off <<= 1) ss += __shfl_xor(ss, off);
  float rn = 1.0f / fmaxf(sqrtf(ss), EPSV);
  an[wv][lane]      = a0 * rn;
  an[wv][64 + lane] = a1 * rn;
  __syncthreads();

  float acc = 0.f;
#pragma unroll 8
  for (int d = 0; d < D; ++d) acc += an[wv][d] * protnT[d * NCLS + lane];
  out[(size_t)i * NCLS + lane] = taop[0] * acc;
}

// ---------------------------------------------------------------------------
extern "C" void kernel_launch(void* const* d_in, const int* in_sizes, int n_in,
                              void* d_out, int out_size, void* d_ws, size_t ws_size,
                              hipStream_t stream) {
  const float* x   = (const float*)d_in[0];
  const float* tao = (const float*)d_in[1];
  float* out = (float*)d_out;

  // workspace layout, ~19.5 MB total
  float*    qn     = (float*)d_ws;                    // 8192*128 f32 (4 MB)
  short*    qh     = (short*)(qn + (size_t)M * D);    // 2 MB bf16
  int*      segcnt = (int*)(qh + (size_t)M * D);      // 8192*16 = 512 KB
  unsigned* cand   = (unsigned*)(segcnt + (size_t)M * SJ);  // 12.6 MB packed
  float*    kval   = (float*)(cand + (size_t)M * SJ * CAPB);
  int*      kidx   = (int*)(kval + (size_t)M * KTOP);
  float*    protnT = (float*)(kidx + (size_t)M * KTOP);     // 128*64

  k0_proto<<<NCLS, 64, 0, stream>>>(x, protnT);
  k1_qnorm<<<M / 4, 256, 0, stream>>>(x, qn, qh);
  k2f<<<(M / 64) * SJ, 256, 0, stream>>>(qh, segcnt, cand);
  k_rr<<<M / 4, 256, 0, stream>>>(qn, segcnt, cand, kval, kidx);
  k3_out<<<M / 4, 256, 0, stream>>>(x, kval, kidx, protnT, tao, out);
}

// Round 20
// 100.020 us; speedup vs baseline: 2.5717x; 1.4608x over previous
//
#include <hip/hip_runtime.h>
#include <hip/hip_bf16.h>
#include <math.h>

// Problem constants (N_WAY=64, K_SHOT=5, Q_QUERY=128, D_FEAT=128)
#define M     8192      // n*q query rows
#define D     128       // feature dim
#define NCLS  64        // n classes
#define KSHOT 5
#define XROW  133       // (k+q) rows per class in x
#define KTOP  9
#define EPSV  1e-8f

// Threshold filter + exact certificate (R13) + packed-value selection (R18)
// + bisection select (R19):
//   k2f packs (bf16(v)<<16 | j) for v >= TAU_LO into per-(row,j-split)
//   segments (LDS-counter emission, zero global atomics). k_rr finds the
//   9th-largest STORED value via 16-step integer bisection (positive bf16
//   bit pattern is order-isomorphic), exact-re-dots only stored >=
//   v9s - 2*EPS_STORE (provable superset of exact top-9), certifies
//   exact-9th > TAU_LO + EPS_DOT, else inline exact full-row fallback.
// R18 lesson: per-lane top-9 lists + 6-round butterfly merge = ~12k VALU
//   cyc/wave (L2-warm replays same 88us as cold -> compute-bound, not mem).
#define TAU_LO    0.21f
#define EPS_DOT   0.005f
#define EPS_STORE 0.008f    // mfma err 0.004 + bf16 truncation 0.004
#define CAPB      24        // per-(row, j-split) segment capacity (lambda ~4.3)

// k2f: MFMA filter pass. Block = 64 i (4 waves x 16-i subs) x 512 j (SJ=16).
#define SJ    16
#define JPB   (M / SJ)      // 512 j per block
#define NTIL  (JPB / 16)    // 32 j-tiles of 16
#define NRND  6             // max pair rounds in k_rr (16*24/64 = 6)

typedef __attribute__((__ext_vector_type__(8))) short bf16v8;  // 8 bf16 = 4 VGPR
typedef __attribute__((__ext_vector_type__(4))) float f32v4;

// ---------------------------------------------------------------------------
// register-resident top-K with (value desc, index asc) tie-break, matching
// jax.lax.top_k set semantics; arrival-order independent for distinct indices.
template <int KN>
__device__ __forceinline__ void topk_insert(float (&kv)[KN], int (&ki)[KN],
                                            float v, int j) {
  if (v > kv[KN - 1] || (v == kv[KN - 1] && j < ki[KN - 1])) {
    float cv = v; int cj = j;
#pragma unroll
    for (int t = 0; t < KN; ++t) {
      bool b = (cv > kv[t]) || (cv == kv[t] && cj < ki[t]);
      float tv = kv[t]; int ti_ = ki[t];
      kv[t] = b ? cv : tv;  ki[t] = b ? cj : ti_;
      cv   = b ? tv : cv;   cj   = b ? ti_ : cj;
    }
  }
}

// ---------------------------------------------------------------------------
__global__ void k0_proto(const float* __restrict__ x, float* __restrict__ protnT) {
  int c = blockIdx.x;
  int lane = threadIdx.x;
  const float* base = x + (size_t)(c * XROW) * D;
  float a0 = 0.f, a1 = 0.f;
#pragma unroll
  for (int s = 0; s < KSHOT; ++s) {
    a0 += base[s * D + lane];
    a1 += base[s * D + 64 + lane];
  }
  a0 *= 0.2f; a1 *= 0.2f;
  float ss = a0 * a0 + a1 * a1;
#pragma unroll
  for (int off = 1; off < 64; off <<= 1) ss += __shfl_xor(ss, off);
  float rn = 1.0f / fmaxf(sqrtf(ss), EPSV);
  protnT[lane * NCLS + c]        = a0 * rn;
  protnT[(lane + 64) * NCLS + c] = a1 * rn;
}

// ---------------------------------------------------------------------------
// k1: L2-normalize query rows -> qn (f32) and qh (bf16).
__global__ void k1_qnorm(const float* __restrict__ x, float* __restrict__ qn,
                         short* __restrict__ qh) {
  int lane = threadIdx.x & 63;
  int wv = threadIdx.x >> 6;
  int r = blockIdx.x * 4 + wv;
  int xr = (r >> 7) * XROW + KSHOT + (r & 127);
  const float* src = x + (size_t)xr * D;
  float v0 = src[lane], v1 = src[64 + lane];
  float ss = v0 * v0 + v1 * v1;
#pragma unroll
  for (int off = 1; off < 64; off <<= 1) ss += __shfl_xor(ss, off);
  float rn = 1.0f / fmaxf(sqrtf(ss), EPSV);
  float q0 = v0 * rn, q1 = v1 * rn;
  qn[(size_t)r * D + lane]      = q0;
  qn[(size_t)r * D + 64 + lane] = q1;
  __hip_bfloat16 h0 = __float2bfloat16(q0);
  __hip_bfloat16 h1 = __float2bfloat16(q1);
  qh[(size_t)r * D + lane]      = *(short*)&h0;
  qh[(size_t)r * D + 64 + lane] = *(short*)&h1;
}

// ---------------------------------------------------------------------------
// k2f: bf16 MFMA + threshold filter. LDS-staged double-buffered j-tile,
// LDS per-row counters, per-(row, j-split) segments of packed (bf16(v)<<16|j).
// D layout (m89-verified): i-col = lane&15, j-row = (lane>>4)*4 + reg.
// (Unchanged from R17/R18 — every k2f restructure so far regressed.)
__global__ __launch_bounds__(256) void
k2f(const short* __restrict__ qh, int* __restrict__ segcnt,
    unsigned* __restrict__ cand) {
  __shared__ __align__(16) short jh[2][16 * D];   // 2 x 4 KB j-tile
  __shared__ int lcnt[64];

  const int tid  = threadIdx.x;
  const int l    = tid & 63;
  const int w    = tid >> 6;
  const int ib   = blockIdx.x >> 4;        // 128 i-strips of 64
  const int js   = blockIdx.x & (SJ - 1);  // 16 j-splits
  const int i0   = ib * 64;
  const int j0s  = js * JPB;

  if (tid < 64) lcnt[tid] = 0;

  const bf16v8* qh8 = (const bf16v8*)qh;
  const int lg   = l >> 4;                 // k-group 0..3
  const int arow = l & 15;
  const int lrow = w * 16 + arow;          // local row 0..63
  const int myi  = i0 + lrow;              // this lane's i-row

  bf16v8 bh[4];
#pragma unroll
  for (int kk = 0; kk < 4; ++kk)
    bh[kk] = qh8[(size_t)myi * 16 + kk * 4 + lg];

  const int srow = tid >> 4;
  const int schk = tid & 15;
  const int sslot = srow * 16 + (schk ^ (srow & 7));
  int rslot[4];
#pragma unroll
  for (int kk = 0; kk < 4; ++kk)
    rslot[kk] = arow * 16 + ((kk * 4 + lg) ^ (arow & 7));

  unsigned* seg = cand + ((size_t)myi * SJ + js) * CAPB;

  bf16v8 sa = qh8[(size_t)(j0s + srow) * 16 + schk];
  ((bf16v8*)jh[0])[sslot] = sa;
  sa = qh8[(size_t)(j0s + 16 + srow) * 16 + schk];
  __syncthreads();                         // covers lcnt init + buf0

  for (int t = 0; t < NTIL; ++t) {
    if (t + 1 < NTIL) {
      ((bf16v8*)jh[(t + 1) & 1])[sslot] = sa;
      if (t + 2 < NTIL)
        sa = qh8[(size_t)(j0s + (t + 2) * 16 + srow) * 16 + schk];
    }

    const bf16v8* H = (const bf16v8*)jh[t & 1];
    f32v4 a0 = {0.f, 0.f, 0.f, 0.f};
    f32v4 a1 = {0.f, 0.f, 0.f, 0.f};
    a0 = __builtin_amdgcn_mfma_f32_16x16x32_bf16(H[rslot[0]], bh[0], a0, 0, 0, 0);
    a1 = __builtin_amdgcn_mfma_f32_16x16x32_bf16(H[rslot[1]], bh[1], a1, 0, 0, 0);
    a0 = __builtin_amdgcn_mfma_f32_16x16x32_bf16(H[rslot[2]], bh[2], a0, 0, 0, 0);
    a1 = __builtin_amdgcn_mfma_f32_16x16x32_bf16(H[rslot[3]], bh[3], a1, 0, 0, 0);
    f32v4 s = a0 + a1;

    const int jb = j0s + t * 16 + lg * 4;
#pragma unroll
    for (int u = 0; u < 4; ++u) {
      if (s[u] >= TAU_LO) {                // ~0.9% of values
        int slot = atomicAdd(&lcnt[lrow], 1);   // LDS atomic
        if (slot < CAPB)
          seg[slot] = (__float_as_uint(s[u]) & 0xFFFF0000u) | (unsigned)(jb + u);
      }
    }

    __syncthreads();
  }

  if (tid < 64)
    segcnt[(size_t)(i0 + tid) * SJ + js] = lcnt[tid];
}

// ---------------------------------------------------------------------------
// k_rr v3: lane-parallel pair load -> 16-step integer bisection for the
// 9th-largest stored value (no per-lane lists, no butterfly merge) ->
// exact re-dot of stored >= v9s - 2*EPS_STORE (provable superset) ->
// certificate; inline exact full-row fallback for the P~1e-13 residue.
__global__ void k_rr(const float* __restrict__ qn, const int* __restrict__ segcnt,
                     const unsigned* __restrict__ cand,
                     float* __restrict__ kval, int* __restrict__ kidx) {
  __shared__ float qi_s[4][D];
  int lane = threadIdx.x & 63;
  int wv   = threadIdx.x >> 6;
  int i = blockIdx.x * 4 + wv;

  float qi0 = qn[(size_t)i * D + lane];
  float qi1 = qn[(size_t)i * D + 64 + lane];

  // --- segment counts + prefix scan (lanes 0..15) ---
  int sc = (lane < SJ) ? segcnt[(size_t)i * SJ + lane] : 0;
  bool bad = __any(lane < SJ && sc > CAPB);
  int pre = sc;
#pragma unroll
  for (int off = 1; off < 16; off <<= 1) {
    int o = __shfl_up(pre, off, 16);
    if ((lane & 15) >= off) pre += o;
  }
  int b[SJ];                               // inclusive prefix, all lanes
#pragma unroll
  for (int k = 0; k < SJ; ++k) b[k] = __shfl(pre, k);
  const int ct = b[SJ - 1];
  bad = bad || (ct < KTOP);

  // --- lane-parallel packed-pair load (6 predicated rounds, NO inserts) ---
  const unsigned* crow = cand + (size_t)i * SJ * CAPB;
  float vv[NRND]; int jj[NRND];
#pragma unroll
  for (int r = 0; r < NRND; ++r) {
    int t = r * 64 + lane;
    bool valid = t < ct;
    int s = 0, off = 0;
#pragma unroll
    for (int k = 0; k < SJ; ++k) {         // b nondecreasing -> cmov scan
      bool ge = t >= b[k];
      s   = ge ? k + 1 : s;
      off = ge ? b[k] : off;
    }
    unsigned u = valid ? crow[s * CAPB + (t - off)] : 0u;
    vv[r] = __uint_as_float(u & 0xFFFF0000u);   // exact bf16 payload (>=0)
    jj[r] = (int)(u & 8191u);
  }

  // --- bisect the 9th-largest stored value on the u16 bit pattern ---
  // (all stored values positive -> bit ordering == value ordering;
  //  invalid lanes carry 0 and never count for mid >= 1)
  int lo = 0, hi = 65535;
  while (lo < hi) {                        // 16 uniform iterations
    int mid = (lo + hi + 1) >> 1;
    unsigned um = (unsigned)mid << 16;
    int cnt = 0;
#pragma unroll
    for (int r = 0; r < NRND; ++r)
      cnt += (int)__popcll(__ballot(__float_as_uint(vv[r]) >= um));
    if (cnt >= KTOP) lo = mid; else hi = mid - 1;
  }
  const float th = __uint_as_float((unsigned)lo << 16) - 2.0f * EPS_STORE;

  // --- exact re-dot of the borderline set (~14/row) ---
  float kv[KTOP]; int ki[KTOP];
#pragma unroll
  for (int t = 0; t < KTOP; ++t) { kv[t] = -INFINITY; ki[t] = 0x7fffffff; }
  if (!bad) {
#pragma unroll
    for (int r = 0; r < NRND; ++r) {
      unsigned long long mask = __ballot(vv[r] >= th);   // invalids are 0 < th
      while (mask) {
        int bl = (int)__ffsll((long long)mask) - 1;
        mask &= mask - 1;
        int jc = __shfl(jj[r], bl);        // wave-uniform
        float p = qi0 * qn[(size_t)jc * D + lane] +
                  qi1 * qn[(size_t)jc * D + 64 + lane];
#pragma unroll
        for (int off = 1; off < 64; off <<= 1) p += __shfl_xor(p, off);
        topk_insert<KTOP>(kv, ki, p, jc);
      }
    }
  }

  // --- certificate; else inline exact full-row fallback ---
  if (bad || kv[KTOP - 1] <= TAU_LO + EPS_DOT) {
    qi_s[wv][lane]      = qi0;
    qi_s[wv][64 + lane] = qi1;
#pragma unroll
    for (int t = 0; t < KTOP; ++t) { kv[t] = -INFINITY; ki[t] = 0x7fffffff; }
    const float4* qi4 = (const float4*)qi_s[wv];
    for (int jb = 0; jb < M; jb += 64) {
      int j = jb + lane;
      const float4* qj = (const float4*)(qn + (size_t)j * D);
      float dot = 0.f;
#pragma unroll 8
      for (int ch = 0; ch < 32; ++ch) {
        float4 a = qi4[ch], bq = qj[ch];
        dot += a.x * bq.x + a.y * bq.y + a.z * bq.z + a.w * bq.w;
      }
      topk_insert<KTOP>(kv, ki, dot, j);
    }
#pragma unroll
    for (int off = 1; off < 64; off <<= 1) {
      float pv[KTOP]; int pj[KTOP];
#pragma unroll
      for (int t = 0; t < KTOP; ++t) {
        pv[t] = __shfl_xor(kv[t], off);
        pj[t] = __shfl_xor(ki[t], off);
      }
#pragma unroll
      for (int t = 0; t < KTOP; ++t) topk_insert<KTOP>(kv, ki, pv[t], pj[t]);
    }
  }

  if (lane == 0) {
#pragma unroll
    for (int t = 0; t < KTOP; ++t) {
      kval[(size_t)i * KTOP + t] = kv[t];
      kidx[(size_t)i * KTOP + t] = ki[t];
    }
  }
}

// ---------------------------------------------------------------------------
// k3: mutual mask + softmax over <=9 entries + adapted query + normalize +
// project on normalized prototypes, scale by tao. One wave per query row.
__global__ void k3_out(const float* __restrict__ x, const float* __restrict__ kval,
                       const int* __restrict__ kidx, const float* __restrict__ protnT,
                       const float* __restrict__ taop, float* __restrict__ out) {
  __shared__ float sw[4][KTOP];
  __shared__ int   sj[4][KTOP];
  __shared__ float an[4][D];
  int lane = threadIdx.x & 63;
  int wv   = threadIdx.x >> 6;
  int i = blockIdx.x * 4 + wv;

  float v = -INFINITY; int jt = 0; bool mut = false;
  if (lane < KTOP) {
    v  = kval[(size_t)i * KTOP + lane];
    jt = kidx[(size_t)i * KTOP + lane];
    const int* oj = kidx + (size_t)jt * KTOP;
#pragma unroll
    for (int t = 0; t < KTOP; ++t) mut = mut || (oj[t] == i);
  }
  float lv = mut ? v : -INFINITY;
#pragma unroll
  for (int off = 1; off < 16; off <<= 1) lv = fmaxf(lv, __shfl_xor(lv, off));
  float wexp = mut ? expf(v - lv) : 0.f;    // self is always mutual -> z >= 1
  float z = wexp;
#pragma unroll
  for (int off = 1; off < 16; off <<= 1) z += __shfl_xor(z, off);
  if (lane < KTOP) { sw[wv][lane] = wexp / z; sj[wv][lane] = jt; }
  __syncthreads();

  float a0 = 0.f, a1 = 0.f;
#pragma unroll
  for (int t = 0; t < KTOP; ++t) {
    float wt = sw[wv][t];
    if (wt != 0.f) {
      int j = sj[wv][t];
      int xr = (j >> 7) * XROW + KSHOT + (j & 127);
      const float* qr = x + (size_t)xr * D;
      a0 += wt * qr[lane];
      a1 += wt * qr[64 + lane];
    }
  }
  float ss = a0 * a0 + a1 * a1;
#pragma unroll
  for (int off = 1; off < 64; off <<= 1) ss += __shfl_xor(ss, off);
  float rn = 1.0f / fmaxf(sqrtf(ss), EPSV);
  an[wv][lane]      = a0 * rn;
  an[wv][64 + lane] = a1 * rn;
  __syncthreads();

  float acc = 0.f;
#pragma unroll 8
  for (int d = 0; d < D; ++d) acc += an[wv][d] * protnT[d * NCLS + lane];
  out[(size_t)i * NCLS + lane] = taop[0] * acc;
}

// ---------------------------------------------------------------------------
extern "C" void kernel_launch(void* const* d_in, const int* in_sizes, int n_in,
                              void* d_out, int out_size, void* d_ws, size_t ws_size,
                              hipStream_t stream) {
  const float* x   = (const float*)d_in[0];
  const float* tao = (const float*)d_in[1];
  float* out = (float*)d_out;

  // workspace layout, ~19.5 MB total
  float*    qn     = (float*)d_ws;                    // 8192*128 f32 (4 MB)
  short*    qh     = (short*)(qn + (size_t)M * D);    // 2 MB bf16
  int*      segcnt = (int*)(qh + (size_t)M * D);      // 8192*16 = 512 KB
  unsigned* cand   = (unsigned*)(segcnt + (size_t)M * SJ);  // 12.6 MB packed
  float*    kval   = (float*)(cand + (size_t)M * SJ * CAPB);
  int*      kidx   = (int*)(kval + (size_t)M * KTOP);
  float*    protnT = (float*)(kidx + (size_t)M * KTOP);     // 128*64

  k0_proto<<<NCLS, 64, 0, stream>>>(x, protnT);
  k1_qnorm<<<M / 4, 256, 0, stream>>>(x, qn, qh);
  k2f<<<(M / 64) * SJ, 256, 0, stream>>>(qh, segcnt, cand);
  k_rr<<<M / 4, 256, 0, stream>>>(qn, segcnt, cand, kval, kidx);
  k3_out<<<M / 4, 256, 0, stream>>>(x, kval, kidx, protnT, tao, out);
}

// Round 21
// 98.738 us; speedup vs baseline: 2.6051x; 1.0130x over previous
//
#include <hip/hip_runtime.h>
#include <hip/hip_bf16.h>
#include <math.h>

// Problem constants (N_WAY=64, K_SHOT=5, Q_QUERY=128, D_FEAT=128)
#define M     8192      // n*q query rows
#define D     128       // feature dim
#define NCLS  64        // n classes
#define KSHOT 5
#define XROW  133       // (k+q) rows per class in x
#define KTOP  9
#define EPSV  1e-8f

// Threshold filter + exact certificate (R13) + packed-value segments (R18)
// + bisection select (R19) + 128-i blocks (R20):
//   k2f packs (bf16(v)<<16 | j) for v >= TAU_LO into per-(row,j-split)
//   segments (LDS-counter emission, zero global atomics). k_rr finds the
//   9th-largest STORED value via 16-step integer bisection, exact-re-dots
//   only stored >= v9s - 2*EPS_STORE (provable superset of exact top-9),
//   certifies exact-9th > TAU_LO + EPS_DOT, else inline full-row fallback.
// R20: block covers 128 i (4 waves x 2 i-subs); same ds_read A-frags feed
//   both i-subs -> 32 MFMA per staged tile (vs 16), halving stage+barrier
//   cost per MFMA (R19: k2f 41us at 16% MfmaUtil, no pipe saturated).
#define TAU_LO    0.21f
#define EPS_DOT   0.005f
#define EPS_STORE 0.008f    // mfma err 0.004 + bf16 truncation 0.004
#define CAPB      24        // per-(row, j-split) segment capacity (lambda ~4.3)

#define BI    128           // i rows per block
#define SJ    16
#define JPB   (M / SJ)      // 512 j per block
#define NTIL  (JPB / 16)    // 32 j-tiles of 16
#define NRND  6             // max pair rounds in k_rr (16*24/64 = 6)

typedef __attribute__((__ext_vector_type__(8))) short bf16v8;  // 8 bf16 = 4 VGPR
typedef __attribute__((__ext_vector_type__(4))) float f32v4;

// ---------------------------------------------------------------------------
// register-resident top-K with (value desc, index asc) tie-break, matching
// jax.lax.top_k set semantics; arrival-order independent for distinct indices.
template <int KN>
__device__ __forceinline__ void topk_insert(float (&kv)[KN], int (&ki)[KN],
                                            float v, int j) {
  if (v > kv[KN - 1] || (v == kv[KN - 1] && j < ki[KN - 1])) {
    float cv = v; int cj = j;
#pragma unroll
    for (int t = 0; t < KN; ++t) {
      bool b = (cv > kv[t]) || (cv == kv[t] && cj < ki[t]);
      float tv = kv[t]; int ti_ = ki[t];
      kv[t] = b ? cv : tv;  ki[t] = b ? cj : ti_;
      cv   = b ? tv : cv;   cj   = b ? ti_ : cj;
    }
  }
}

// ---------------------------------------------------------------------------
__global__ void k0_proto(const float* __restrict__ x, float* __restrict__ protnT) {
  int c = blockIdx.x;
  int lane = threadIdx.x;
  const float* base = x + (size_t)(c * XROW) * D;
  float a0 = 0.f, a1 = 0.f;
#pragma unroll
  for (int s = 0; s < KSHOT; ++s) {
    a0 += base[s * D + lane];
    a1 += base[s * D + 64 + lane];
  }
  a0 *= 0.2f; a1 *= 0.2f;
  float ss = a0 * a0 + a1 * a1;
#pragma unroll
  for (int off = 1; off < 64; off <<= 1) ss += __shfl_xor(ss, off);
  float rn = 1.0f / fmaxf(sqrtf(ss), EPSV);
  protnT[lane * NCLS + c]        = a0 * rn;
  protnT[(lane + 64) * NCLS + c] = a1 * rn;
}

// ---------------------------------------------------------------------------
// k1: L2-normalize query rows -> qn (f32) and qh (bf16).
__global__ void k1_qnorm(const float* __restrict__ x, float* __restrict__ qn,
                         short* __restrict__ qh) {
  int lane = threadIdx.x & 63;
  int wv = threadIdx.x >> 6;
  int r = blockIdx.x * 4 + wv;
  int xr = (r >> 7) * XROW + KSHOT + (r & 127);
  const float* src = x + (size_t)xr * D;
  float v0 = src[lane], v1 = src[64 + lane];
  float ss = v0 * v0 + v1 * v1;
#pragma unroll
  for (int off = 1; off < 64; off <<= 1) ss += __shfl_xor(ss, off);
  float rn = 1.0f / fmaxf(sqrtf(ss), EPSV);
  float q0 = v0 * rn, q1 = v1 * rn;
  qn[(size_t)r * D + lane]      = q0;
  qn[(size_t)r * D + 64 + lane] = q1;
  __hip_bfloat16 h0 = __float2bfloat16(q0);
  __hip_bfloat16 h1 = __float2bfloat16(q1);
  qh[(size_t)r * D + lane]      = *(short*)&h0;
  qh[(size_t)r * D + 64 + lane] = *(short*)&h1;
}

// ---------------------------------------------------------------------------
// k2f: bf16 MFMA + threshold filter. LDS-staged double-buffered j-tile,
// 128 i-rows/block (2 i-subs share each A-frag ds_read), LDS per-row
// counters, per-(row, j-split) segments of packed (bf16(v)<<16|j).
// D layout (m89-verified): i-col = lane&15, j-row = (lane>>4)*4 + reg.
__global__ __launch_bounds__(256) void
k2f(const short* __restrict__ qh, int* __restrict__ segcnt,
    unsigned* __restrict__ cand) {
  __shared__ __align__(16) short jh[2][16 * D];   // 2 x 4 KB j-tile
  __shared__ int lcnt[BI];

  const int tid  = threadIdx.x;
  const int l    = tid & 63;
  const int w    = tid >> 6;
  const int ib   = blockIdx.x >> 4;        // 64 i-strips of 128
  const int js   = blockIdx.x & (SJ - 1);  // 16 j-splits
  const int i0   = ib * BI;
  const int j0s  = js * JPB;

  if (tid < BI) lcnt[tid] = 0;

  const bf16v8* qh8 = (const bf16v8*)qh;
  const int lg   = l >> 4;                 // k-group 0..3
  const int arow = l & 15;
  const int lrow = w * 16 + arow;          // local row 0..63 (i-sub 0)
  const int myi  = i0 + lrow;              // i-sub 0 row
  const int myi2 = myi + 64;               // i-sub 1 row

  // persistent i-side B fragments for BOTH i-subs
  bf16v8 bh[4], bg[4];
#pragma unroll
  for (int kk = 0; kk < 4; ++kk) {
    bh[kk] = qh8[(size_t)myi  * 16 + kk * 4 + lg];
    bg[kk] = qh8[(size_t)myi2 * 16 + kk * 4 + lg];
  }

  const int srow = tid >> 4;
  const int schk = tid & 15;
  const int sslot = srow * 16 + (schk ^ (srow & 7));
  int rslot[4];
#pragma unroll
  for (int kk = 0; kk < 4; ++kk)
    rslot[kk] = arow * 16 + ((kk * 4 + lg) ^ (arow & 7));

  unsigned* seg  = cand + ((size_t)myi  * SJ + js) * CAPB;
  unsigned* seg2 = cand + ((size_t)myi2 * SJ + js) * CAPB;

  bf16v8 sa = qh8[(size_t)(j0s + srow) * 16 + schk];
  ((bf16v8*)jh[0])[sslot] = sa;
  sa = qh8[(size_t)(j0s + 16 + srow) * 16 + schk];
  __syncthreads();                         // covers lcnt init + buf0

  for (int t = 0; t < NTIL; ++t) {
    if (t + 1 < NTIL) {
      ((bf16v8*)jh[(t + 1) & 1])[sslot] = sa;
      if (t + 2 < NTIL)
        sa = qh8[(size_t)(j0s + (t + 2) * 16 + srow) * 16 + schk];
    }

    const bf16v8* H = (const bf16v8*)jh[t & 1];
    f32v4 a0 = {0.f, 0.f, 0.f, 0.f};
    f32v4 a1 = {0.f, 0.f, 0.f, 0.f};
    f32v4 c0 = {0.f, 0.f, 0.f, 0.f};
    f32v4 c1 = {0.f, 0.f, 0.f, 0.f};
#pragma unroll
    for (int kk = 0; kk < 4; ++kk) {
      bf16v8 ah = H[rslot[kk]];            // one ds_read feeds both i-subs
      if (kk & 1) {
        a1 = __builtin_amdgcn_mfma_f32_16x16x32_bf16(ah, bh[kk], a1, 0, 0, 0);
        c1 = __builtin_amdgcn_mfma_f32_16x16x32_bf16(ah, bg[kk], c1, 0, 0, 0);
      } else {
        a0 = __builtin_amdgcn_mfma_f32_16x16x32_bf16(ah, bh[kk], a0, 0, 0, 0);
        c0 = __builtin_amdgcn_mfma_f32_16x16x32_bf16(ah, bg[kk], c0, 0, 0, 0);
      }
    }
    f32v4 s = a0 + a1;
    f32v4 r2 = c0 + c1;

    const int jb = j0s + t * 16 + lg * 4;
#pragma unroll
    for (int u = 0; u < 4; ++u) {
      if (s[u] >= TAU_LO) {                // ~0.9% of values
        int slot = atomicAdd(&lcnt[lrow], 1);
        if (slot < CAPB)
          seg[slot] = (__float_as_uint(s[u]) & 0xFFFF0000u) | (unsigned)(jb + u);
      }
      if (r2[u] >= TAU_LO) {
        int slot = atomicAdd(&lcnt[lrow + 64], 1);
        if (slot < CAPB)
          seg2[slot] = (__float_as_uint(r2[u]) & 0xFFFF0000u) | (unsigned)(jb + u);
      }
    }

    __syncthreads();
  }

  if (tid < BI)
    segcnt[(size_t)(i0 + tid) * SJ + js] = lcnt[tid];
}

// ---------------------------------------------------------------------------
// k_rr v3: lane-parallel pair load -> 16-step integer bisection for the
// 9th-largest stored value -> exact re-dot of stored >= v9s - 2*EPS_STORE
// (provable superset) -> certificate; inline exact full-row fallback.
__global__ void k_rr(const float* __restrict__ qn, const int* __restrict__ segcnt,
                     const unsigned* __restrict__ cand,
                     float* __restrict__ kval, int* __restrict__ kidx) {
  __shared__ float qi_s[4][D];
  int lane = threadIdx.x & 63;
  int wv   = threadIdx.x >> 6;
  int i = blockIdx.x * 4 + wv;

  float qi0 = qn[(size_t)i * D + lane];
  float qi1 = qn[(size_t)i * D + 64 + lane];

  // --- segment counts + prefix scan (lanes 0..15) ---
  int sc = (lane < SJ) ? segcnt[(size_t)i * SJ + lane] : 0;
  bool bad = __any(lane < SJ && sc > CAPB);
  int pre = sc;
#pragma unroll
  for (int off = 1; off < 16; off <<= 1) {
    int o = __shfl_up(pre, off, 16);
    if ((lane & 15) >= off) pre += o;
  }
  int b[SJ];                               // inclusive prefix, all lanes
#pragma unroll
  for (int k = 0; k < SJ; ++k) b[k] = __shfl(pre, k);
  const int ct = b[SJ - 1];
  bad = bad || (ct < KTOP);

  // --- lane-parallel packed-pair load (6 predicated rounds, NO inserts) ---
  const unsigned* crow = cand + (size_t)i * SJ * CAPB;
  float vv[NRND]; int jj[NRND];
#pragma unroll
  for (int r = 0; r < NRND; ++r) {
    int t = r * 64 + lane;
    bool valid = t < ct;
    int s = 0, off = 0;
#pragma unroll
    for (int k = 0; k < SJ; ++k) {         // b nondecreasing -> cmov scan
      bool ge = t >= b[k];
      s   = ge ? k + 1 : s;
      off = ge ? b[k] : off;
    }
    unsigned u = valid ? crow[s * CAPB + (t - off)] : 0u;
    vv[r] = __uint_as_float(u & 0xFFFF0000u);   // exact bf16 payload (>=0)
    jj[r] = (int)(u & 8191u);
  }

  // --- bisect the 9th-largest stored value on the u16 bit pattern ---
  int lo = 0, hi = 65535;
  while (lo < hi) {                        // 16 uniform iterations
    int mid = (lo + hi + 1) >> 1;
    unsigned um = (unsigned)mid << 16;
    int cnt = 0;
#pragma unroll
    for (int r = 0; r < NRND; ++r)
      cnt += (int)__popcll(__ballot(__float_as_uint(vv[r]) >= um));
    if (cnt >= KTOP) lo = mid; else hi = mid - 1;
  }
  const float th = __uint_as_float((unsigned)lo << 16) - 2.0f * EPS_STORE;

  // --- exact re-dot of the borderline set (~14/row) ---
  float kv[KTOP]; int ki[KTOP];
#pragma unroll
  for (int t = 0; t < KTOP; ++t) { kv[t] = -INFINITY; ki[t] = 0x7fffffff; }
  if (!bad) {
#pragma unroll
    for (int r = 0; r < NRND; ++r) {
      unsigned long long mask = __ballot(vv[r] >= th);   // invalids are 0 < th
      while (mask) {
        int bl = (int)__ffsll((long long)mask) - 1;
        mask &= mask - 1;
        int jc = __shfl(jj[r], bl);        // wave-uniform
        float p = qi0 * qn[(size_t)jc * D + lane] +
                  qi1 * qn[(size_t)jc * D + 64 + lane];
#pragma unroll
        for (int off = 1; off < 64; off <<= 1) p += __shfl_xor(p, off);
        topk_insert<KTOP>(kv, ki, p, jc);
      }
    }
  }

  // --- certificate; else inline exact full-row fallback ---
  if (bad || kv[KTOP - 1] <= TAU_LO + EPS_DOT) {
    qi_s[wv][lane]      = qi0;
    qi_s[wv][64 + lane] = qi1;
#pragma unroll
    for (int t = 0; t < KTOP; ++t) { kv[t] = -INFINITY; ki[t] = 0x7fffffff; }
    const float4* qi4 = (const float4*)qi_s[wv];
    for (int jb = 0; jb < M; jb += 64) {
      int j = jb + lane;
      const float4* qj = (const float4*)(qn + (size_t)j * D);
      float dot = 0.f;
#pragma unroll 8
      for (int ch = 0; ch < 32; ++ch) {
        float4 a = qi4[ch], bq = qj[ch];
        dot += a.x * bq.x + a.y * bq.y + a.z * bq.z + a.w * bq.w;
      }
      topk_insert<KTOP>(kv, ki, dot, j);
    }
#pragma unroll
    for (int off = 1; off < 64; off <<= 1) {
      float pv[KTOP]; int pj[KTOP];
#pragma unroll
      for (int t = 0; t < KTOP; ++t) {
        pv[t] = __shfl_xor(kv[t], off);
        pj[t] = __shfl_xor(ki[t], off);
      }
#pragma unroll
      for (int t = 0; t < KTOP; ++t) topk_insert<KTOP>(kv, ki, pv[t], pj[t]);
    }
  }

  if (lane == 0) {
#pragma unroll
    for (int t = 0; t < KTOP; ++t) {
      kval[(size_t)i * KTOP + t] = kv[t];
      kidx[(size_t)i * KTOP + t] = ki[t];
    }
  }
}

// ---------------------------------------------------------------------------
// k3: mutual mask + softmax over <=9 entries + adapted query + normalize +
// project on normalized prototypes, scale by tao. One wave per query row.
__global__ void k3_out(const float* __restrict__ x, const float* __restrict__ kval,
                       const int* __restrict__ kidx, const float* __restrict__ protnT,
                       const float* __restrict__ taop, float* __restrict__ out) {
  __shared__ float sw[4][KTOP];
  __shared__ int   sj[4][KTOP];
  __shared__ float an[4][D];
  int lane = threadIdx.x & 63;
  int wv   = threadIdx.x >> 6;
  int i = blockIdx.x * 4 + wv;

  float v = -INFINITY; int jt = 0; bool mut = false;
  if (lane < KTOP) {
    v  = kval[(size_t)i * KTOP + lane];
    jt = kidx[(size_t)i * KTOP + lane];
    const int* oj = kidx + (size_t)jt * KTOP;
#pragma unroll
    for (int t = 0; t < KTOP; ++t) mut = mut || (oj[t] == i);
  }
  float lv = mut ? v : -INFINITY;
#pragma unroll
  for (int off = 1; off < 16; off <<= 1) lv = fmaxf(lv, __shfl_xor(lv, off));
  float wexp = mut ? expf(v - lv) : 0.f;    // self is always mutual -> z >= 1
  float z = wexp;
#pragma unroll
  for (int off = 1; off < 16; off <<= 1) z += __shfl_xor(z, off);
  if (lane < KTOP) { sw[wv][lane] = wexp / z; sj[wv][lane] = jt; }
  __syncthreads();

  float a0 = 0.f, a1 = 0.f;
#pragma unroll
  for (int t = 0; t < KTOP; ++t) {
    float wt = sw[wv][t];
    if (wt != 0.f) {
      int j = sj[wv][t];
      int xr = (j >> 7) * XROW + KSHOT + (j & 127);
      const float* qr = x + (size_t)xr * D;
      a0 += wt * qr[lane];
      a1 += wt * qr[64 + lane];
    }
  }
  float ss = a0 * a0 + a1 * a1;
#pragma unroll
  for (int off = 1; off < 64; off <<= 1) ss += __shfl_xor(ss, off);
  float rn = 1.0f / fmaxf(sqrtf(ss), EPSV);
  an[wv][lane]      = a0 * rn;
  an[wv][64 + lane] = a1 * rn;
  __syncthreads();

  float acc = 0.f;
#pragma unroll 8
  for (int d = 0; d < D; ++d) acc += an[wv][d] * protnT[d * NCLS + lane];
  out[(size_t)i * NCLS + lane] = taop[0] * acc;
}

// ---------------------------------------------------------------------------
extern "C" void kernel_launch(void* const* d_in, const int* in_sizes, int n_in,
                              void* d_out, int out_size, void* d_ws, size_t ws_size,
                              hipStream_t stream) {
  const float* x   = (const float*)d_in[0];
  const float* tao = (const float*)d_in[1];
  float* out = (float*)d_out;

  // workspace layout, ~19.5 MB total
  float*    qn     = (float*)d_ws;                    // 8192*128 f32 (4 MB)
  short*    qh     = (short*)(qn + (size_t)M * D);    // 2 MB bf16
  int*      segcnt = (int*)(qh + (size_t)M * D);      // 8192*16 = 512 KB
  unsigned* cand   = (unsigned*)(segcnt + (size_t)M * SJ);  // 12.6 MB packed
  float*    kval   = (float*)(cand + (size_t)M * SJ * CAPB);
  int*      kidx   = (int*)(kval + (size_t)M * KTOP);
  float*    protnT = (float*)(kidx + (size_t)M * KTOP);     // 128*64

  k0_proto<<<NCLS, 64, 0, stream>>>(x, protnT);
  k1_qnorm<<<M / 4, 256, 0, stream>>>(x, qn, qh);
  k2f<<<(M / BI) * SJ, 256, 0, stream>>>(qh, segcnt, cand);
  k_rr<<<M / 4, 256, 0, stream>>>(qn, segcnt, cand, kval, kidx);
  k3_out<<<M / 4, 256, 0, stream>>>(x, kval, kidx, protnT, tao, out);
}